// Round 9
// baseline (412.033 us; speedup 1.0000x reference)
//
#include <hip/hip_runtime.h>
#include <cfloat>

#define Dm 256
#define HW 1024
#define NE 2048
#define L_TOT 32768
#define QOFF 8388608   // B*C*H*W
#define TAU 0.01f

typedef __attribute__((ext_vector_type(8))) short bf16x8;
typedef __attribute__((ext_vector_type(4))) float f32x4;
typedef const __attribute__((address_space(1))) unsigned int* as1_u32p;
typedef __attribute__((address_space(3))) unsigned int* as3_u32p;

#define GLL(gp, lp) __builtin_amdgcn_global_load_lds((as1_u32p)(gp), (as3_u32p)(lp), 16, 0, 0)

__device__ __forceinline__ unsigned short f2bf(float x) {
    unsigned u = __float_as_uint(x);
    unsigned r = (u + 0x7fffu + ((u >> 16) & 1u)) >> 16;
    return (unsigned short)r;
}
__device__ __forceinline__ float bf2f(unsigned short h) {
    return __uint_as_float(((unsigned)h) << 16);
}

// ---------------- K1 (fallback only): code norms ----------------
__global__ void k_enorm(const float* __restrict__ emb, float* __restrict__ enorm) {
    int w = threadIdx.x >> 6, lane = threadIdx.x & 63;
    int n = blockIdx.x * 4 + w;
    const float4 v = *reinterpret_cast<const float4*>(emb + (size_t)n * Dm + lane * 4);
    double s = (double)v.x * v.x + (double)v.y * v.y + (double)v.z * v.z + (double)v.w * v.w;
    #pragma unroll
    for (int off = 32; off; off >>= 1) s += __shfl_xor(s, off);
    if (lane == 0) enorm[n] = (float)s;
}

// ---------------- fused: split Z (transpose) + split E + norms + ws zeroing ----------------
__global__ __launch_bounds__(256) void k_split(
    const float* __restrict__ z, const float* __restrict__ emb,
    unsigned short* __restrict__ z_hi, unsigned short* __restrict__ z_lo,
    unsigned short* __restrict__ e_hi, unsigned short* __restrict__ e_lo,
    float* __restrict__ enorm, float* __restrict__ zn_part,
    float* __restrict__ used, int* __restrict__ flag_cnt)
{
    __shared__ unsigned short zh[32][260];
    __shared__ unsigned short zl[32][260];
    __shared__ double zsum[4];
    const int t = threadIdx.x;
    const int w = t >> 6, lane = t & 63;

    // ws zeroing (replaces memset launch)
    if (blockIdx.x >= 16 && blockIdx.x < 24) used[(blockIdx.x - 16) * 256 + t] = 0.f;
    if (blockIdx.x == 24 && t == 0) *flag_cnt = 0;

    // fused E-split: waves 0,1 each handle one emb row (2048 rows / 1024 blocks)
    if (w < 2) {
        int n = blockIdx.x * 2 + w;
        const float4 v = *reinterpret_cast<const float4*>(emb + (size_t)n * Dm + lane * 4);
        float vv[4] = { v.x, v.y, v.z, v.w };
        double s = (double)v.x * v.x + (double)v.y * v.y + (double)v.z * v.z + (double)v.w * v.w;
        #pragma unroll
        for (int off = 32; off; off >>= 1) s += __shfl_xor(s, off);
        if (lane == 0) enorm[n] = (float)s;
        ushort4 h4, l4;
        unsigned short* hp = (unsigned short*)&h4;
        unsigned short* lp = (unsigned short*)&l4;
        #pragma unroll
        for (int j = 0; j < 4; ++j) {
            unsigned short h = f2bf(vv[j]);
            hp[j] = h;
            lp[j] = f2bf(vv[j] - bf2f(h));
        }
        *reinterpret_cast<ushort4*>(e_hi + (size_t)n * Dm + lane * 4) = h4;
        *reinterpret_cast<ushort4*>(e_lo + (size_t)n * Dm + lane * 4) = l4;
    }

    // Z split+transpose + ||z||^2 partial
    const int b  = blockIdx.x >> 5;
    const int p0 = (blockIdx.x & 31) * 32;
    const int pp = t & 31, cb = t >> 5;
    const float* zb = z + (size_t)b * (Dm * HW) + p0 + pp;
    float zs = 0.f;
    for (int ci = 0; ci < 32; ++ci) {
        int c = ci * 8 + cb;
        float x = zb[(size_t)c * HW];
        zs = fmaf(x, x, zs);
        unsigned short h = f2bf(x);
        zh[pp][c] = h;
        zl[pp][c] = f2bf(x - bf2f(h));
    }
    double d = zs;
    #pragma unroll
    for (int off = 32; off; off >>= 1) d += __shfl_xor(d, off);
    if ((t & 63) == 0) zsum[w] = d;
    __syncthreads();
    if (t == 0) zn_part[blockIdx.x] = (float)(zsum[0] + zsum[1] + zsum[2] + zsum[3]);
    const int l0 = b * 1024 + p0;
    #pragma unroll
    for (int r = 0; r < 8; ++r) {
        int id = r * 256 + t;
        int row = id >> 6, ch = id & 63;
        *reinterpret_cast<ushort4*>(z_hi + (size_t)(l0 + row) * Dm + ch * 4) =
            *reinterpret_cast<ushort4*>(&zh[row][ch * 4]);
        *reinterpret_cast<ushort4*>(z_lo + (size_t)(l0 + row) * Dm + ch * 4) =
            *reinterpret_cast<ushort4*>(&zl[row][ch * 4]);
    }
}

// ---------------- K2: bf16-split score GEMM + top-2 argmin (r4-proven, verbatim) ----------------
__global__ __launch_bounds__(512, 4) void k_score2(
    const unsigned short* __restrict__ z_hi, const unsigned short* __restrict__ z_lo,
    const unsigned short* __restrict__ e_hi, const unsigned short* __restrict__ e_lo,
    const float* __restrict__ enorm,
    float* __restrict__ pd1, float* __restrict__ pd2, int* __restrict__ pi1)
{
    __shared__ unsigned short lds[2][2][128 * 64];   // [buf][A=0/B=1][row*64+k]

    const int t    = threadIdx.x;
    const int lane = t & 63, w = t >> 6;
    const int wm = w >> 2, wn = w & 3;
    const int c15 = lane & 15, g4 = lane >> 4;

    const int bx = blockIdx.x;
    const int wg = (bx & 7) * 64 + (bx >> 3);
    const int mi = wg >> 1, ni = wg & 1;
    const int l0 = mi * 128;
    const int nbase = ni * 1024;

    auto stage = [&](int buf, const unsigned short* As, const unsigned short* Bs,
                     int nB0, int k0) {
        #pragma unroll
        for (int r = 0; r < 2; ++r) {
            int id  = r * 512 + t;
            int row = id >> 3, ch = id & 7;
            int chg = ch ^ (row & 7);
            GLL(As + (size_t)(l0 + row) * Dm + k0 + chg * 8, &lds[buf][0][id * 8]);
            GLL(Bs + (size_t)(nB0 + row) * Dm + k0 + chg * 8, &lds[buf][1][id * 8]);
        }
    };

    float d1[4][4], d2[4][4]; int i1[4][4];
    #pragma unroll
    for (int m = 0; m < 4; ++m)
        #pragma unroll
        for (int r = 0; r < 4; ++r) { d1[m][r] = 3.4e38f; d2[m][r] = 3.4e38f; i1[m][r] = 0; }

    stage(0, z_hi, e_hi, nbase, 0);
    __syncthreads();

    int cur = 0, it = 0;
    for (int nt = 0; nt < 8; ++nt) {
        f32x4 acc[4][2];
        #pragma unroll
        for (int m = 0; m < 4; ++m)
            #pragma unroll
            for (int n = 0; n < 2; ++n) acc[m][n] = (f32x4){0.f, 0.f, 0.f, 0.f};

        for (int kt = 0; kt < 12; ++kt, ++it) {
            if (it + 1 < 96) {
                int nit = it + 1;
                int nnt = nit / 12;
                int nkt = nit - nnt * 12;
                int nterm = nkt >> 2, nkc = nkt & 3;
                const unsigned short* As = (nterm == 1) ? z_lo : z_hi;
                const unsigned short* Bs = (nterm == 2) ? e_lo : e_hi;
                stage(cur ^ 1, As, Bs, nbase + nnt * 128, nkc * 64);
            }
            const unsigned short* Ab = &lds[cur][0][0];
            const unsigned short* Bb = &lds[cur][1][0];
            #pragma unroll
            for (int ks = 0; ks < 2; ++ks) {
                bf16x8 af[4], bfr[2];
                #pragma unroll
                for (int m = 0; m < 4; ++m) {
                    int row = wm * 64 + m * 16 + c15;
                    int cc  = ks * 4 + g4;
                    af[m] = *reinterpret_cast<const bf16x8*>(
                        &Ab[row * 64 + ((cc ^ (row & 7)) << 3)]);
                }
                #pragma unroll
                for (int n = 0; n < 2; ++n) {
                    int row = wn * 32 + n * 16 + c15;
                    int cc  = ks * 4 + g4;
                    bfr[n] = *reinterpret_cast<const bf16x8*>(
                        &Bb[row * 64 + ((cc ^ (row & 7)) << 3)]);
                }
                __builtin_amdgcn_s_setprio(1);
                #pragma unroll
                for (int m = 0; m < 4; ++m)
                    #pragma unroll
                    for (int n = 0; n < 2; ++n)
                        acc[m][n] = __builtin_amdgcn_mfma_f32_16x16x32_bf16(
                            af[m], bfr[n], acc[m][n], 0, 0, 0);
                __builtin_amdgcn_s_setprio(0);
            }
            __syncthreads();
            cur ^= 1;
        }
        int n0 = nbase + nt * 128;
        #pragma unroll
        for (int n = 0; n < 2; ++n) {
            int ng = n0 + wn * 32 + n * 16 + c15;
            float en = enorm[ng];
            #pragma unroll
            for (int m = 0; m < 4; ++m)
                #pragma unroll
                for (int r = 0; r < 4; ++r) {
                    float s = fmaf(-2.f, acc[m][n][r], en);
                    if (s < d1[m][r]) { d2[m][r] = d1[m][r]; d1[m][r] = s; i1[m][r] = ng; }
                    else if (s < d2[m][r]) d2[m][r] = s;
                }
        }
    }

    #pragma unroll
    for (int off = 1; off <= 8; off <<= 1) {
        #pragma unroll
        for (int m = 0; m < 4; ++m)
            #pragma unroll
            for (int r = 0; r < 4; ++r) {
                float od1 = __shfl_xor(d1[m][r], off);
                int   oi1 = __shfl_xor(i1[m][r], off);
                float od2 = __shfl_xor(d2[m][r], off);
                float nd2 = fminf(fminf(d2[m][r], od2), fmaxf(d1[m][r], od1));
                if (od1 < d1[m][r] || (od1 == d1[m][r] && oi1 < i1[m][r])) {
                    d1[m][r] = od1; i1[m][r] = oi1;
                }
                d2[m][r] = nd2;
            }
    }

    float* rs1 = (float*)&lds[0][0][0];
    float* rs2 = rs1 + 3 * 128;
    int*   ri  = (int*)(rs2 + 3 * 128);
    if (wn > 0 && c15 == 0) {
        int s = wn - 1;
        #pragma unroll
        for (int m = 0; m < 4; ++m)
            #pragma unroll
            for (int r = 0; r < 4; ++r) {
                int q = wm * 64 + m * 16 + g4 * 4 + r;
                rs1[s * 128 + q] = d1[m][r];
                rs2[s * 128 + q] = d2[m][r];
                ri [s * 128 + q] = i1[m][r];
            }
    }
    __syncthreads();
    if (wn == 0 && c15 == 0) {
        #pragma unroll
        for (int m = 0; m < 4; ++m)
            #pragma unroll
            for (int r = 0; r < 4; ++r) {
                int q = wm * 64 + m * 16 + g4 * 4 + r;
                float bd1 = d1[m][r], bd2 = d2[m][r]; int bi1 = i1[m][r];
                #pragma unroll
                for (int s = 0; s < 3; ++s) {
                    float od1 = rs1[s * 128 + q], od2 = rs2[s * 128 + q];
                    int   oi1 = ri [s * 128 + q];
                    float nd2 = fminf(fminf(bd2, od2), fmaxf(bd1, od1));
                    if (od1 < bd1 || (od1 == bd1 && oi1 < bi1)) { bd1 = od1; bi1 = oi1; }
                    bd2 = nd2;
                }
                int gq = l0 + q;
                pd1[ni * L_TOT + gq] = bd1;
                pd2[ni * L_TOT + gq] = bd2;
                pi1[ni * L_TOT + gq] = bi1;
            }
    }
}

// ---------------- fused merge + gather (tier 1) ----------------
__global__ __launch_bounds__(256) void k_mg(
    const float* __restrict__ pd1, const float* __restrict__ pd2,
    const int* __restrict__ pi1, const float* __restrict__ emb,
    int* __restrict__ ws_idx, float* __restrict__ out_idxf,
    float* __restrict__ used, int* __restrict__ flag_cnt,
    int* __restrict__ flag_list, float* __restrict__ d1_part,
    float* __restrict__ outq)
{
    __shared__ int sidx[64];
    __shared__ float eldT[Dm][65];
    const int t = threadIdx.x;
    const int l0 = blockIdx.x * 64;
    const int b = l0 >> 10, p0 = l0 & 1023;

    if (t < 64) {
        int gq = l0 + t;
        float d1 = pd1[gq], d2 = pd2[gq]; int i1 = pi1[gq];
        float od1 = pd1[L_TOT + gq], od2 = pd2[L_TOT + gq];
        int   oi1 = pi1[L_TOT + gq];
        float nd2 = fminf(fminf(d2, od2), fmaxf(d1, od1));
        if (od1 < d1 || (od1 == d1 && oi1 < i1)) { d1 = od1; i1 = oi1; }
        d2 = nd2;
        ws_idx[gq] = i1;
        out_idxf[gq] = (float)i1;
        if (d2 - d1 < TAU) {
            int pos = atomicAdd(flag_cnt, 1);
            flag_list[pos] = gq;
        } else {
            used[i1] = 1.0f;
        }
        sidx[t] = i1;
        float s = d1;
        #pragma unroll
        for (int off = 32; off; off >>= 1) s += __shfl_xor(s, off);
        if (t == 0) d1_part[blockIdx.x] = s;
    }
    __syncthreads();

    int w = t >> 6, lane = t & 63;
    for (int r = 0; r < 16; ++r) {
        int q = r * 4 + w;
        const float4 v = *reinterpret_cast<const float4*>(emb + (size_t)sidx[q] * Dm + lane * 4);
        eldT[lane * 4 + 0][q] = v.x; eldT[lane * 4 + 1][q] = v.y;
        eldT[lane * 4 + 2][q] = v.z; eldT[lane * 4 + 3][q] = v.w;
    }
    __syncthreads();
    const size_t obase = (size_t)b * (Dm * HW) + p0 + lane;
    #pragma unroll 4
    for (int it = 0; it < 64; ++it) {
        int c = w * 64 + it;
        outq[obase + (size_t)c * HW] = eldT[c][lane];
    }
}

// ---------------- merge only (tier 2, r7-proven) ----------------
__global__ __launch_bounds__(256) void k_merge(
    const float* __restrict__ pd1, const float* __restrict__ pd2,
    const int* __restrict__ pi1, int* __restrict__ ws_idx,
    float* __restrict__ out_idxf, float* __restrict__ used,
    int* __restrict__ flag_cnt, int* __restrict__ flag_list,
    float* __restrict__ d1_part)
{
    __shared__ float sdl[256];
    int tt = threadIdx.x;
    int gq = blockIdx.x * 256 + tt;
    float d1 = pd1[gq], d2 = pd2[gq]; int i1 = pi1[gq];
    {
        float od1 = pd1[L_TOT + gq], od2 = pd2[L_TOT + gq];
        int   oi1 = pi1[L_TOT + gq];
        float nd2 = fminf(fminf(d2, od2), fmaxf(d1, od1));
        if (od1 < d1 || (od1 == d1 && oi1 < i1)) { d1 = od1; i1 = oi1; }
        d2 = nd2;
    }
    ws_idx[gq] = i1;
    out_idxf[gq] = (float)i1;
    if (d2 - d1 < TAU) {
        int pos = atomicAdd(flag_cnt, 1);
        flag_list[pos] = gq;
    } else {
        used[i1] = 1.0f;
    }
    sdl[tt] = d1;
    __syncthreads();
    for (int st = 128; st; st >>= 1) {
        if (tt < st) sdl[tt] += sdl[tt + st];
        __syncthreads();
    }
    if (tt == 0) d1_part[blockIdx.x] = sdl[0];
}

// ---------------- fallback fp32 argmin (round-1 proven) ----------------
#define BM 64
#define BN 128
#define BK 64
__global__ __launch_bounds__(256, 2) void k_argmin_f32(
    const float* __restrict__ z, const float* __restrict__ emb,
    const float* __restrict__ enorm, int* __restrict__ ws_idx,
    float* __restrict__ out_idxf, float* __restrict__ used,
    int* __restrict__ flag_cnt, int* __restrict__ flag_list)
{
    __shared__ float zl[BK][BM];
    __shared__ float el[BK][BN + 4];
    __shared__ float rd1[4][64];
    __shared__ int   ri1[4][64];
    __shared__ float rd2[4][64];

    const int t  = threadIdx.x;
    const int tq = t & 15;
    const int tn = t >> 4;
    const int l0 = blockIdx.x * BM;
    const int b  = l0 >> 10, p0 = l0 & 1023;
    const float* zb = z + (size_t)b * (Dm * HW) + p0;

    float d1[4], d2[4]; int i1[4];
    #pragma unroll
    for (int i = 0; i < 4; ++i) { d1[i] = FLT_MAX; d2[i] = FLT_MAX; i1[i] = 0; }

    for (int nt = 0; nt < NE / BN; ++nt) {
        const int n0 = nt * BN;
        float acc[4][8];
        #pragma unroll
        for (int i = 0; i < 4; ++i)
            #pragma unroll
            for (int j = 0; j < 8; ++j) acc[i][j] = 0.f;

        for (int kc = 0; kc < Dm / BK; ++kc) {
            __syncthreads();
            #pragma unroll
            for (int r = 0; r < 4; ++r) {
                int f = r * 256 + t;
                int kk = f >> 4, q4 = (f & 15) << 2;
                float4 v = *reinterpret_cast<const float4*>(zb + (size_t)(kc * BK + kk) * HW + q4);
                *reinterpret_cast<float4*>(&zl[kk][q4]) = v;
            }
            #pragma unroll
            for (int r = 0; r < 8; ++r) {
                int f = r * 256 + t;
                int n = f >> 4, k4 = (f & 15) << 2;
                float4 v = *reinterpret_cast<const float4*>(emb + (size_t)(n0 + n) * Dm + kc * BK + k4);
                el[k4 + 0][n] = v.x; el[k4 + 1][n] = v.y;
                el[k4 + 2][n] = v.z; el[k4 + 3][n] = v.w;
            }
            __syncthreads();
            #pragma unroll 4
            for (int kk = 0; kk < BK; ++kk) {
                float4 zf = *reinterpret_cast<const float4*>(&zl[kk][tq << 2]);
                float4 e0 = *reinterpret_cast<const float4*>(&el[kk][tn << 3]);
                float4 e1 = *reinterpret_cast<const float4*>(&el[kk][(tn << 3) + 4]);
                float zr[4] = { zf.x, zf.y, zf.z, zf.w };
                float er[8] = { e0.x, e0.y, e0.z, e0.w, e1.x, e1.y, e1.z, e1.w };
                #pragma unroll
                for (int i = 0; i < 4; ++i)
                    #pragma unroll
                    for (int j = 0; j < 8; ++j)
                        acc[i][j] = fmaf(zr[i], er[j], acc[i][j]);
            }
        }
        #pragma unroll
        for (int j = 0; j < 8; ++j) {
            int ng = n0 + (tn << 3) + j;
            float en = enorm[ng];
            #pragma unroll
            for (int i = 0; i < 4; ++i) {
                float s = fmaf(-2.f, acc[i][j], en);
                if (s < d1[i]) { d2[i] = d1[i]; d1[i] = s; i1[i] = ng; }
                else if (s < d2[i]) d2[i] = s;
            }
        }
    }
    #pragma unroll
    for (int off = 16; off <= 32; off <<= 1) {
        #pragma unroll
        for (int i = 0; i < 4; ++i) {
            float od1 = __shfl_xor(d1[i], off);
            int   oi1 = __shfl_xor(i1[i], off);
            float od2 = __shfl_xor(d2[i], off);
            float nd2 = fminf(fminf(d2[i], od2), fmaxf(d1[i], od1));
            bool take = (od1 < d1[i]) || (od1 == d1[i] && oi1 < i1[i]);
            if (take) { d1[i] = od1; i1[i] = oi1; }
            d2[i] = nd2;
        }
    }
    int w = t >> 6;
    if ((t & 63) < 16) {
        #pragma unroll
        for (int i = 0; i < 4; ++i) {
            rd1[w][(tq << 2) + i] = d1[i];
            ri1[w][(tq << 2) + i] = i1[i];
            rd2[w][(tq << 2) + i] = d2[i];
        }
    }
    __syncthreads();
    if (t < 64) {
        float bd1 = rd1[0][t]; int bi1 = ri1[0][t]; float bd2 = rd2[0][t];
        #pragma unroll
        for (int ww = 1; ww < 4; ++ww) {
            float od1 = rd1[ww][t]; int oi1 = ri1[ww][t]; float od2 = rd2[ww][t];
            float nd2 = fminf(fminf(bd2, od2), fmaxf(bd1, od1));
            if (od1 < bd1 || (od1 == bd1 && oi1 < bi1)) { bd1 = od1; bi1 = oi1; }
            bd2 = nd2;
        }
        int l = l0 + t;
        ws_idx[l] = bi1;
        out_idxf[l] = (float)bi1;
        if (bd2 - bd1 < TAU) {
            int pos = atomicAdd(flag_cnt, 1);
            flag_list[pos] = l;
        } else {
            used[bi1] = 1.0f;
        }
    }
}

// ---------------- K_refine: fp64-exact argmin, coalesced per-wave-per-code ----------------
// One wave per code (codes == w mod 4, ascending -> lowest-index tie-break preserved).
// Lane reads float4 of emb row (coalesced 1 KB/code); 64-lane fp64 butterfly reduce;
// lane-0 trajectory is self-consistent; 4-wave lexicographic merge.
__global__ __launch_bounds__(256) void k_refine(
    const float* __restrict__ z, const float* __restrict__ emb,
    const int* __restrict__ flag_cnt, const int* __restrict__ flag_list,
    int* __restrict__ ws_idx, float* __restrict__ out_idxf,
    float* __restrict__ used, float* __restrict__ outq)
{
    __shared__ float zrow[Dm];
    __shared__ double wbd[4];
    __shared__ int    wbi[4];
    __shared__ int    bestn;
    const int t = threadIdx.x, w = t >> 6, lane = t & 63;
    const int nf = *flag_cnt;
    for (int fi = blockIdx.x; fi < nf; fi += gridDim.x) {
        const int l = flag_list[fi];
        const int b = l >> 10, p = l & 1023;
        const float* zq = z + (size_t)b * (Dm * HW) + p;
        __syncthreads();
        zrow[t] = zq[(size_t)t * HW];
        __syncthreads();
        const double z0 = zrow[lane * 4 + 0], z1 = zrow[lane * 4 + 1];
        const double z2 = zrow[lane * 4 + 2], z3 = zrow[lane * 4 + 3];
        double bd = DBL_MAX; int bi = 0;
        for (int n = w; n < NE; n += 4) {
            const float4 e4 = *reinterpret_cast<const float4*>(emb + (size_t)n * Dm + lane * 4);
            double e0 = e4.x, e1 = e4.y, e2 = e4.z, e3 = e4.w;
            double s = e0 * (e0 - 2.0 * z0) + e1 * (e1 - 2.0 * z1)
                     + e2 * (e2 - 2.0 * z2) + e3 * (e3 - 2.0 * z3);
            #pragma unroll
            for (int off = 1; off <= 32; off <<= 1) s += __shfl_xor(s, off);
            if (s < bd) { bd = s; bi = n; }   // ascending n per wave -> strict '<'
        }
        if (lane == 0) { wbd[w] = bd; wbi[w] = bi; }
        __syncthreads();
        if (t == 0) {
            double b0 = wbd[0]; int i0 = wbi[0];
            #pragma unroll
            for (int ww = 1; ww < 4; ++ww) {
                if (wbd[ww] < b0 || (wbd[ww] == b0 && wbi[ww] < i0)) {
                    b0 = wbd[ww]; i0 = wbi[ww];
                }
            }
            ws_idx[l] = i0;
            out_idxf[l] = (float)i0;
            used[i0] = 1.0f;
            bestn = i0;
        }
        __syncthreads();
        // patch the quantized output row with the exact pick
        outq[(size_t)b * (Dm * HW) + (size_t)t * HW + p] = emb[(size_t)bestn * Dm + t];
    }
}

// ---------------- gather (tier 2, post-refine) ----------------
__global__ __launch_bounds__(256) void k_gather(
    const float* __restrict__ emb, const int* __restrict__ ws_idx,
    float* __restrict__ outq)
{
    __shared__ int sidx[64];
    __shared__ float eldT[Dm][65];
    const int t = threadIdx.x;
    const int l0 = blockIdx.x * 64;
    const int b = l0 >> 10, p0 = l0 & 1023;
    if (t < 64) sidx[t] = ws_idx[l0 + t];
    __syncthreads();
    int w = t >> 6, lane = t & 63;
    for (int r = 0; r < 16; ++r) {
        int q = r * 4 + w;
        const float4 v = *reinterpret_cast<const float4*>(emb + (size_t)sidx[q] * Dm + lane * 4);
        eldT[lane * 4 + 0][q] = v.x; eldT[lane * 4 + 1][q] = v.y;
        eldT[lane * 4 + 2][q] = v.z; eldT[lane * 4 + 3][q] = v.w;
    }
    __syncthreads();
    const size_t obase = (size_t)b * (Dm * HW) + p0 + lane;
    #pragma unroll 4
    for (int it = 0; it < 64; ++it) {
        int c = w * 64 + it;
        outq[obase + (size_t)c * HW] = eldT[c][lane];
    }
}

// ---------------- fallback gather+loss (tier 3) ----------------
__global__ __launch_bounds__(256) void k_gather_loss(
    const float* __restrict__ z, const float* __restrict__ emb,
    const int* __restrict__ ws_idx, float* __restrict__ outq,
    float* __restrict__ partials)
{
    __shared__ int sidx[64];
    __shared__ float eldT[Dm][65];
    __shared__ float wsum[4];
    const int t = threadIdx.x;
    const int l0 = blockIdx.x * 64;
    const int b = l0 >> 10, p0 = l0 & 1023;
    if (t < 64) sidx[t] = ws_idx[l0 + t];
    __syncthreads();
    int w = t >> 6, lane = t & 63;
    for (int r = 0; r < 16; ++r) {
        int q = r * 4 + w;
        const float4 v = *reinterpret_cast<const float4*>(emb + (size_t)sidx[q] * Dm + lane * 4);
        eldT[lane * 4 + 0][q] = v.x; eldT[lane * 4 + 1][q] = v.y;
        eldT[lane * 4 + 2][q] = v.z; eldT[lane * 4 + 3][q] = v.w;
    }
    __syncthreads();
    float ls = 0.f;
    const size_t obase = (size_t)b * (Dm * HW) + p0 + lane;
    for (int it = 0; it < 64; ++it) {
        int c = w * 64 + it;
        size_t o = obase + (size_t)c * HW;
        float qv = eldT[c][lane];
        float zv = z[o];
        outq[o] = qv;
        float df = qv - zv;
        ls = fmaf(df, df, ls);
    }
    #pragma unroll
    for (int off = 32; off; off >>= 1) ls += __shfl_xor(ls, off);
    if (lane == 0) wsum[w] = ls;
    __syncthreads();
    if (t == 0) partials[blockIdx.x] = wsum[0] + wsum[1] + wsum[2] + wsum[3];
}

// ---------------- final: loss = (Sum||z||^2 + Sum d1)/count, used count ----------------
__global__ void k_final(const float* __restrict__ zn_part, const float* __restrict__ d1_part,
                        int nd1, const float* __restrict__ used,
                        float* __restrict__ out_loss, float* __restrict__ out_used)
{
    __shared__ double s1[256];
    __shared__ float  s2[256];
    int t = threadIdx.x;
    double a = 0.0;
    for (int i = t; i < 1024; i += 256) a += (double)zn_part[i];
    for (int i = t; i < nd1; i += 256) a += (double)d1_part[i];
    float u = 0.f;
    for (int i = t; i < NE; i += 256) u += used[i];
    s1[t] = a; s2[t] = u;
    __syncthreads();
    for (int st = 128; st; st >>= 1) {
        if (t < st) { s1[t] += s1[t + st]; s2[t] += s2[t + st]; }
        __syncthreads();
    }
    if (t == 0) { *out_loss = (float)(s1[0] / 8388608.0); *out_used = s2[0]; }
}

// ---------------- fallback final ----------------
__global__ void k_final_fb(const float* __restrict__ partials, const float* __restrict__ used,
                           float* __restrict__ out_loss, float* __restrict__ out_used)
{
    __shared__ float s1[256], s2[256];
    int t = threadIdx.x;
    float a = partials[t] + partials[t + 256];
    float u = 0.f;
    for (int i = t; i < NE; i += 256) u += used[i];
    s1[t] = a; s2[t] = u;
    __syncthreads();
    for (int st = 128; st; st >>= 1) {
        if (t < st) { s1[t] += s1[t + st]; s2[t] += s2[t + st]; }
        __syncthreads();
    }
    if (t == 0) { *out_loss = s1[0] / 8388608.f; *out_used = s2[0]; }
}

extern "C" void kernel_launch(void* const* d_in, const int* in_sizes, int n_in,
                              void* d_out, int out_size, void* d_ws, size_t ws_size,
                              hipStream_t stream) {
    const float* z   = (const float*)d_in[0];
    const float* emb = (const float*)d_in[1];
    float* out      = (float*)d_out;
    float* outq     = out;
    float* out_loss = out + QOFF;
    float* out_idxf = out + QOFF + 1;
    float* out_used = out + QOFF + 1 + L_TOT;

    float* ws       = (float*)d_ws;
    float* enorm    = ws;                         // [0, 2048)
    float* used     = ws + 2048;                  // [2048, 4096)
    float* zn_part  = ws + 4096;                  // [4096, 5120)
    float* d1_part  = ws + 5120;                  // [5120, 5632)  512
    int*   flag_cnt = (int*)(ws + 5632);          // 1 (+pad)
    int*   ws_idx   = (int*)(ws + 5888);          // 32768
    int*   flag_list= (int*)(ws + 5888 + L_TOT);  // 32768 -> ends 71424

    // tier-1 partials in ws (avoids outq read/write race in fused k_mg)
    float* pd1w = ws + 71680;                     // 65536
    float* pd2w = ws + 137216;                    // 65536
    int*   pi1w = (int*)(ws + 202752);            // 65536 -> ends 268288 floats

    size_t bf_bytes = 2ull * (NE + L_TOT) * Dm * sizeof(unsigned short);  // 35651584
    size_t need_t1 = 268288ull * 4 + bf_bytes;    // ~36.7 MB
    size_t need_t2 = 71680ull * 4 + bf_bytes;     // ~35.9 MB

    if (ws_size >= need_t1) {
        unsigned short* e_hi = (unsigned short*)(ws + 268288);
        unsigned short* e_lo = e_hi + (size_t)NE * Dm;
        unsigned short* z_hi = e_lo + (size_t)NE * Dm;
        unsigned short* z_lo = z_hi + (size_t)L_TOT * Dm;
        k_split<<<1024, 256, 0, stream>>>(z, emb, z_hi, z_lo, e_hi, e_lo,
                                          enorm, zn_part, used, flag_cnt);
        k_score2<<<512, 512, 0, stream>>>(z_hi, z_lo, e_hi, e_lo, enorm, pd1w, pd2w, pi1w);
        k_mg<<<L_TOT / 64, 256, 0, stream>>>(pd1w, pd2w, pi1w, emb, ws_idx, out_idxf,
                                             used, flag_cnt, flag_list, d1_part, outq);
        k_refine<<<256, 256, 0, stream>>>(z, emb, flag_cnt, flag_list, ws_idx, out_idxf,
                                          used, outq);
        k_final<<<1, 256, 0, stream>>>(zn_part, d1_part, 512, used, out_loss, out_used);
    } else if (ws_size >= need_t2) {
        unsigned short* e_hi = (unsigned short*)(ws + 71680);
        unsigned short* e_lo = e_hi + (size_t)NE * Dm;
        unsigned short* z_hi = e_lo + (size_t)NE * Dm;
        unsigned short* z_lo = z_hi + (size_t)L_TOT * Dm;
        float* pd1 = outq;
        float* pd2 = outq + 2 * L_TOT;
        int*   pi1 = (int*)(outq + 4 * L_TOT);
        k_split<<<1024, 256, 0, stream>>>(z, emb, z_hi, z_lo, e_hi, e_lo,
                                          enorm, zn_part, used, flag_cnt);
        k_score2<<<512, 512, 0, stream>>>(z_hi, z_lo, e_hi, e_lo, enorm, pd1, pd2, pi1);
        k_merge<<<L_TOT / 256, 256, 0, stream>>>(pd1, pd2, pi1, ws_idx, out_idxf, used,
                                                 flag_cnt, flag_list, d1_part);
        k_refine<<<256, 256, 0, stream>>>(z, emb, flag_cnt, flag_list, ws_idx, out_idxf,
                                          used, outq);
        k_gather<<<L_TOT / 64, 256, 0, stream>>>(emb, ws_idx, outq);
        k_final<<<1, 256, 0, stream>>>(zn_part, d1_part, 128, used, out_loss, out_used);
    } else {
        hipMemsetAsync(used, 0, (size_t)3584 * 4, stream);
        k_enorm<<<NE / 4, 256, 0, stream>>>(emb, enorm);
        k_argmin_f32<<<L_TOT / BM, 256, 0, stream>>>(z, emb, enorm, ws_idx, out_idxf, used,
                                                     flag_cnt, flag_list);
        k_refine<<<256, 256, 0, stream>>>(z, emb, flag_cnt, flag_list, ws_idx, out_idxf,
                                          used, outq);
        k_gather_loss<<<L_TOT / 64, 256, 0, stream>>>(z, emb, ws_idx, outq, zn_part);
        k_final_fb<<<1, 256, 0, stream>>>(zn_part, used, out_loss, out_used);
    }
}

// Round 10
// 240.879 us; speedup vs baseline: 1.7105x; 1.7105x over previous
//
#include <hip/hip_runtime.h>
#include <cfloat>

#define Dm 256
#define HW 1024
#define NE 2048
#define L_TOT 32768
#define QOFF 8388608   // B*C*H*W
#define TAU 0.01f

typedef __attribute__((ext_vector_type(8))) short bf16x8;
typedef __attribute__((ext_vector_type(4))) float f32x4;
typedef const __attribute__((address_space(1))) unsigned int* as1_u32p;
typedef __attribute__((address_space(3))) unsigned int* as3_u32p;

#define GLL(gp, lp) __builtin_amdgcn_global_load_lds((as1_u32p)(gp), (as3_u32p)(lp), 16, 0, 0)

__device__ __forceinline__ unsigned short f2bf(float x) {
    unsigned u = __float_as_uint(x);
    unsigned r = (u + 0x7fffu + ((u >> 16) & 1u)) >> 16;
    return (unsigned short)r;
}
__device__ __forceinline__ float bf2f(unsigned short h) {
    return __uint_as_float(((unsigned)h) << 16);
}

// ---------------- K1 (fallback only): code norms ----------------
__global__ void k_enorm(const float* __restrict__ emb, float* __restrict__ enorm) {
    int w = threadIdx.x >> 6, lane = threadIdx.x & 63;
    int n = blockIdx.x * 4 + w;
    const float4 v = *reinterpret_cast<const float4*>(emb + (size_t)n * Dm + lane * 4);
    double s = (double)v.x * v.x + (double)v.y * v.y + (double)v.z * v.z + (double)v.w * v.w;
    #pragma unroll
    for (int off = 32; off; off >>= 1) s += __shfl_xor(s, off);
    if (lane == 0) enorm[n] = (float)s;
}

// ---------------- fused: split Z (transpose) + split E + norms + ws zeroing ----------------
__global__ __launch_bounds__(256) void k_split(
    const float* __restrict__ z, const float* __restrict__ emb,
    unsigned short* __restrict__ z_hi, unsigned short* __restrict__ z_lo,
    unsigned short* __restrict__ e_hi, unsigned short* __restrict__ e_lo,
    float* __restrict__ enorm, float* __restrict__ zn_part,
    float* __restrict__ used, int* __restrict__ flag_cnt)
{
    __shared__ unsigned short zh[32][260];
    __shared__ unsigned short zl[32][260];
    __shared__ double zsum[4];
    const int t = threadIdx.x;
    const int w = t >> 6, lane = t & 63;

    // ws zeroing (replaces memset launch)
    if (blockIdx.x >= 16 && blockIdx.x < 24) used[(blockIdx.x - 16) * 256 + t] = 0.f;
    if (blockIdx.x == 24 && t == 0) *flag_cnt = 0;

    // fused E-split: waves 0,1 each handle one emb row (2048 rows / 1024 blocks)
    if (w < 2) {
        int n = blockIdx.x * 2 + w;
        const float4 v = *reinterpret_cast<const float4*>(emb + (size_t)n * Dm + lane * 4);
        float vv[4] = { v.x, v.y, v.z, v.w };
        double s = (double)v.x * v.x + (double)v.y * v.y + (double)v.z * v.z + (double)v.w * v.w;
        #pragma unroll
        for (int off = 32; off; off >>= 1) s += __shfl_xor(s, off);
        if (lane == 0) enorm[n] = (float)s;
        ushort4 h4, l4;
        unsigned short* hp = (unsigned short*)&h4;
        unsigned short* lp = (unsigned short*)&l4;
        #pragma unroll
        for (int j = 0; j < 4; ++j) {
            unsigned short h = f2bf(vv[j]);
            hp[j] = h;
            lp[j] = f2bf(vv[j] - bf2f(h));
        }
        *reinterpret_cast<ushort4*>(e_hi + (size_t)n * Dm + lane * 4) = h4;
        *reinterpret_cast<ushort4*>(e_lo + (size_t)n * Dm + lane * 4) = l4;
    }

    // Z split+transpose + ||z||^2 partial
    const int b  = blockIdx.x >> 5;
    const int p0 = (blockIdx.x & 31) * 32;
    const int pp = t & 31, cb = t >> 5;
    const float* zb = z + (size_t)b * (Dm * HW) + p0 + pp;
    float zs = 0.f;
    for (int ci = 0; ci < 32; ++ci) {
        int c = ci * 8 + cb;
        float x = zb[(size_t)c * HW];
        zs = fmaf(x, x, zs);
        unsigned short h = f2bf(x);
        zh[pp][c] = h;
        zl[pp][c] = f2bf(x - bf2f(h));
    }
    double d = zs;
    #pragma unroll
    for (int off = 32; off; off >>= 1) d += __shfl_xor(d, off);
    if ((t & 63) == 0) zsum[w] = d;
    __syncthreads();
    if (t == 0) zn_part[blockIdx.x] = (float)(zsum[0] + zsum[1] + zsum[2] + zsum[3]);
    const int l0 = b * 1024 + p0;
    #pragma unroll
    for (int r = 0; r < 8; ++r) {
        int id = r * 256 + t;
        int row = id >> 6, ch = id & 63;
        *reinterpret_cast<ushort4*>(z_hi + (size_t)(l0 + row) * Dm + ch * 4) =
            *reinterpret_cast<ushort4*>(&zh[row][ch * 4]);
        *reinterpret_cast<ushort4*>(z_lo + (size_t)(l0 + row) * Dm + ch * 4) =
            *reinterpret_cast<ushort4*>(&zl[row][ch * 4]);
    }
}

// ---------------- K2: bf16-split score GEMM + top-2 argmin (r4-proven, verbatim) ----------------
__global__ __launch_bounds__(512, 4) void k_score2(
    const unsigned short* __restrict__ z_hi, const unsigned short* __restrict__ z_lo,
    const unsigned short* __restrict__ e_hi, const unsigned short* __restrict__ e_lo,
    const float* __restrict__ enorm,
    float* __restrict__ pd1, float* __restrict__ pd2, int* __restrict__ pi1)
{
    __shared__ unsigned short lds[2][2][128 * 64];   // [buf][A=0/B=1][row*64+k]

    const int t    = threadIdx.x;
    const int lane = t & 63, w = t >> 6;
    const int wm = w >> 2, wn = w & 3;
    const int c15 = lane & 15, g4 = lane >> 4;

    const int bx = blockIdx.x;
    const int wg = (bx & 7) * 64 + (bx >> 3);
    const int mi = wg >> 1, ni = wg & 1;
    const int l0 = mi * 128;
    const int nbase = ni * 1024;

    auto stage = [&](int buf, const unsigned short* As, const unsigned short* Bs,
                     int nB0, int k0) {
        #pragma unroll
        for (int r = 0; r < 2; ++r) {
            int id  = r * 512 + t;
            int row = id >> 3, ch = id & 7;
            int chg = ch ^ (row & 7);
            GLL(As + (size_t)(l0 + row) * Dm + k0 + chg * 8, &lds[buf][0][id * 8]);
            GLL(Bs + (size_t)(nB0 + row) * Dm + k0 + chg * 8, &lds[buf][1][id * 8]);
        }
    };

    float d1[4][4], d2[4][4]; int i1[4][4];
    #pragma unroll
    for (int m = 0; m < 4; ++m)
        #pragma unroll
        for (int r = 0; r < 4; ++r) { d1[m][r] = 3.4e38f; d2[m][r] = 3.4e38f; i1[m][r] = 0; }

    stage(0, z_hi, e_hi, nbase, 0);
    __syncthreads();

    int cur = 0, it = 0;
    for (int nt = 0; nt < 8; ++nt) {
        f32x4 acc[4][2];
        #pragma unroll
        for (int m = 0; m < 4; ++m)
            #pragma unroll
            for (int n = 0; n < 2; ++n) acc[m][n] = (f32x4){0.f, 0.f, 0.f, 0.f};

        for (int kt = 0; kt < 12; ++kt, ++it) {
            if (it + 1 < 96) {
                int nit = it + 1;
                int nnt = nit / 12;
                int nkt = nit - nnt * 12;
                int nterm = nkt >> 2, nkc = nkt & 3;
                const unsigned short* As = (nterm == 1) ? z_lo : z_hi;
                const unsigned short* Bs = (nterm == 2) ? e_lo : e_hi;
                stage(cur ^ 1, As, Bs, nbase + nnt * 128, nkc * 64);
            }
            const unsigned short* Ab = &lds[cur][0][0];
            const unsigned short* Bb = &lds[cur][1][0];
            #pragma unroll
            for (int ks = 0; ks < 2; ++ks) {
                bf16x8 af[4], bfr[2];
                #pragma unroll
                for (int m = 0; m < 4; ++m) {
                    int row = wm * 64 + m * 16 + c15;
                    int cc  = ks * 4 + g4;
                    af[m] = *reinterpret_cast<const bf16x8*>(
                        &Ab[row * 64 + ((cc ^ (row & 7)) << 3)]);
                }
                #pragma unroll
                for (int n = 0; n < 2; ++n) {
                    int row = wn * 32 + n * 16 + c15;
                    int cc  = ks * 4 + g4;
                    bfr[n] = *reinterpret_cast<const bf16x8*>(
                        &Bb[row * 64 + ((cc ^ (row & 7)) << 3)]);
                }
                __builtin_amdgcn_s_setprio(1);
                #pragma unroll
                for (int m = 0; m < 4; ++m)
                    #pragma unroll
                    for (int n = 0; n < 2; ++n)
                        acc[m][n] = __builtin_amdgcn_mfma_f32_16x16x32_bf16(
                            af[m], bfr[n], acc[m][n], 0, 0, 0);
                __builtin_amdgcn_s_setprio(0);
            }
            __syncthreads();
            cur ^= 1;
        }
        int n0 = nbase + nt * 128;
        #pragma unroll
        for (int n = 0; n < 2; ++n) {
            int ng = n0 + wn * 32 + n * 16 + c15;
            float en = enorm[ng];
            #pragma unroll
            for (int m = 0; m < 4; ++m)
                #pragma unroll
                for (int r = 0; r < 4; ++r) {
                    float s = fmaf(-2.f, acc[m][n][r], en);
                    if (s < d1[m][r]) { d2[m][r] = d1[m][r]; d1[m][r] = s; i1[m][r] = ng; }
                    else if (s < d2[m][r]) d2[m][r] = s;
                }
        }
    }

    #pragma unroll
    for (int off = 1; off <= 8; off <<= 1) {
        #pragma unroll
        for (int m = 0; m < 4; ++m)
            #pragma unroll
            for (int r = 0; r < 4; ++r) {
                float od1 = __shfl_xor(d1[m][r], off);
                int   oi1 = __shfl_xor(i1[m][r], off);
                float od2 = __shfl_xor(d2[m][r], off);
                float nd2 = fminf(fminf(d2[m][r], od2), fmaxf(d1[m][r], od1));
                if (od1 < d1[m][r] || (od1 == d1[m][r] && oi1 < i1[m][r])) {
                    d1[m][r] = od1; i1[m][r] = oi1;
                }
                d2[m][r] = nd2;
            }
    }

    float* rs1 = (float*)&lds[0][0][0];
    float* rs2 = rs1 + 3 * 128;
    int*   ri  = (int*)(rs2 + 3 * 128);
    if (wn > 0 && c15 == 0) {
        int s = wn - 1;
        #pragma unroll
        for (int m = 0; m < 4; ++m)
            #pragma unroll
            for (int r = 0; r < 4; ++r) {
                int q = wm * 64 + m * 16 + g4 * 4 + r;
                rs1[s * 128 + q] = d1[m][r];
                rs2[s * 128 + q] = d2[m][r];
                ri [s * 128 + q] = i1[m][r];
            }
    }
    __syncthreads();
    if (wn == 0 && c15 == 0) {
        #pragma unroll
        for (int m = 0; m < 4; ++m)
            #pragma unroll
            for (int r = 0; r < 4; ++r) {
                int q = wm * 64 + m * 16 + g4 * 4 + r;
                float bd1 = d1[m][r], bd2 = d2[m][r]; int bi1 = i1[m][r];
                #pragma unroll
                for (int s = 0; s < 3; ++s) {
                    float od1 = rs1[s * 128 + q], od2 = rs2[s * 128 + q];
                    int   oi1 = ri [s * 128 + q];
                    float nd2 = fminf(fminf(bd2, od2), fmaxf(bd1, od1));
                    if (od1 < bd1 || (od1 == bd1 && oi1 < bi1)) { bd1 = od1; bi1 = oi1; }
                    bd2 = nd2;
                }
                int gq = l0 + q;
                pd1[ni * L_TOT + gq] = bd1;
                pd2[ni * L_TOT + gq] = bd2;
                pi1[ni * L_TOT + gq] = bi1;
            }
    }
}

// ---------------- fused merge + gather (tier 1) ----------------
__global__ __launch_bounds__(256) void k_mg(
    const float* __restrict__ pd1, const float* __restrict__ pd2,
    const int* __restrict__ pi1, const float* __restrict__ emb,
    int* __restrict__ ws_idx, float* __restrict__ out_idxf,
    float* __restrict__ used, int* __restrict__ flag_cnt,
    int* __restrict__ flag_list, float* __restrict__ d1_part,
    float* __restrict__ outq)
{
    __shared__ int sidx[64];
    __shared__ float eldT[Dm][65];
    const int t = threadIdx.x;
    const int l0 = blockIdx.x * 64;
    const int b = l0 >> 10, p0 = l0 & 1023;

    if (t < 64) {
        int gq = l0 + t;
        float d1 = pd1[gq], d2 = pd2[gq]; int i1 = pi1[gq];
        float od1 = pd1[L_TOT + gq], od2 = pd2[L_TOT + gq];
        int   oi1 = pi1[L_TOT + gq];
        float nd2 = fminf(fminf(d2, od2), fmaxf(d1, od1));
        if (od1 < d1 || (od1 == d1 && oi1 < i1)) { d1 = od1; i1 = oi1; }
        d2 = nd2;
        ws_idx[gq] = i1;
        out_idxf[gq] = (float)i1;
        if (d2 - d1 < TAU) {
            int pos = atomicAdd(flag_cnt, 1);
            flag_list[pos] = gq;
        } else {
            used[i1] = 1.0f;
        }
        sidx[t] = i1;
        float s = d1;
        #pragma unroll
        for (int off = 32; off; off >>= 1) s += __shfl_xor(s, off);
        if (t == 0) d1_part[blockIdx.x] = s;
    }
    __syncthreads();

    int w = t >> 6, lane = t & 63;
    for (int r = 0; r < 16; ++r) {
        int q = r * 4 + w;
        const float4 v = *reinterpret_cast<const float4*>(emb + (size_t)sidx[q] * Dm + lane * 4);
        eldT[lane * 4 + 0][q] = v.x; eldT[lane * 4 + 1][q] = v.y;
        eldT[lane * 4 + 2][q] = v.z; eldT[lane * 4 + 3][q] = v.w;
    }
    __syncthreads();
    const size_t obase = (size_t)b * (Dm * HW) + p0 + lane;
    #pragma unroll 4
    for (int it = 0; it < 64; ++it) {
        int c = w * 64 + it;
        outq[obase + (size_t)c * HW] = eldT[c][lane];
    }
}

// ---------------- merge only (tier 2, r7-proven) ----------------
__global__ __launch_bounds__(256) void k_merge(
    const float* __restrict__ pd1, const float* __restrict__ pd2,
    const int* __restrict__ pi1, int* __restrict__ ws_idx,
    float* __restrict__ out_idxf, float* __restrict__ used,
    int* __restrict__ flag_cnt, int* __restrict__ flag_list,
    float* __restrict__ d1_part)
{
    __shared__ float sdl[256];
    int tt = threadIdx.x;
    int gq = blockIdx.x * 256 + tt;
    float d1 = pd1[gq], d2 = pd2[gq]; int i1 = pi1[gq];
    {
        float od1 = pd1[L_TOT + gq], od2 = pd2[L_TOT + gq];
        int   oi1 = pi1[L_TOT + gq];
        float nd2 = fminf(fminf(d2, od2), fmaxf(d1, od1));
        if (od1 < d1 || (od1 == d1 && oi1 < i1)) { d1 = od1; i1 = oi1; }
        d2 = nd2;
    }
    ws_idx[gq] = i1;
    out_idxf[gq] = (float)i1;
    if (d2 - d1 < TAU) {
        int pos = atomicAdd(flag_cnt, 1);
        flag_list[pos] = gq;
    } else {
        used[i1] = 1.0f;
    }
    sdl[tt] = d1;
    __syncthreads();
    for (int st = 128; st; st >>= 1) {
        if (tt < st) sdl[tt] += sdl[tt + st];
        __syncthreads();
    }
    if (tt == 0) d1_part[blockIdx.x] = sdl[0];
}

// ---------------- fallback fp32 argmin (round-1 proven) ----------------
#define BM 64
#define BN 128
#define BK 64
__global__ __launch_bounds__(256, 2) void k_argmin_f32(
    const float* __restrict__ z, const float* __restrict__ emb,
    const float* __restrict__ enorm, int* __restrict__ ws_idx,
    float* __restrict__ out_idxf, float* __restrict__ used,
    int* __restrict__ flag_cnt, int* __restrict__ flag_list)
{
    __shared__ float zl[BK][BM];
    __shared__ float el[BK][BN + 4];
    __shared__ float rd1[4][64];
    __shared__ int   ri1[4][64];
    __shared__ float rd2[4][64];

    const int t  = threadIdx.x;
    const int tq = t & 15;
    const int tn = t >> 4;
    const int l0 = blockIdx.x * BM;
    const int b  = l0 >> 10, p0 = l0 & 1023;
    const float* zb = z + (size_t)b * (Dm * HW) + p0;

    float d1[4], d2[4]; int i1[4];
    #pragma unroll
    for (int i = 0; i < 4; ++i) { d1[i] = FLT_MAX; d2[i] = FLT_MAX; i1[i] = 0; }

    for (int nt = 0; nt < NE / BN; ++nt) {
        const int n0 = nt * BN;
        float acc[4][8];
        #pragma unroll
        for (int i = 0; i < 4; ++i)
            #pragma unroll
            for (int j = 0; j < 8; ++j) acc[i][j] = 0.f;

        for (int kc = 0; kc < Dm / BK; ++kc) {
            __syncthreads();
            #pragma unroll
            for (int r = 0; r < 4; ++r) {
                int f = r * 256 + t;
                int kk = f >> 4, q4 = (f & 15) << 2;
                float4 v = *reinterpret_cast<const float4*>(zb + (size_t)(kc * BK + kk) * HW + q4);
                *reinterpret_cast<float4*>(&zl[kk][q4]) = v;
            }
            #pragma unroll
            for (int r = 0; r < 8; ++r) {
                int f = r * 256 + t;
                int n = f >> 4, k4 = (f & 15) << 2;
                float4 v = *reinterpret_cast<const float4*>(emb + (size_t)(n0 + n) * Dm + kc * BK + k4);
                el[k4 + 0][n] = v.x; el[k4 + 1][n] = v.y;
                el[k4 + 2][n] = v.z; el[k4 + 3][n] = v.w;
            }
            __syncthreads();
            #pragma unroll 4
            for (int kk = 0; kk < BK; ++kk) {
                float4 zf = *reinterpret_cast<const float4*>(&zl[kk][tq << 2]);
                float4 e0 = *reinterpret_cast<const float4*>(&el[kk][tn << 3]);
                float4 e1 = *reinterpret_cast<const float4*>(&el[kk][(tn << 3) + 4]);
                float zr[4] = { zf.x, zf.y, zf.z, zf.w };
                float er[8] = { e0.x, e0.y, e0.z, e0.w, e1.x, e1.y, e1.z, e1.w };
                #pragma unroll
                for (int i = 0; i < 4; ++i)
                    #pragma unroll
                    for (int j = 0; j < 8; ++j)
                        acc[i][j] = fmaf(zr[i], er[j], acc[i][j]);
            }
        }
        #pragma unroll
        for (int j = 0; j < 8; ++j) {
            int ng = n0 + (tn << 3) + j;
            float en = enorm[ng];
            #pragma unroll
            for (int i = 0; i < 4; ++i) {
                float s = fmaf(-2.f, acc[i][j], en);
                if (s < d1[i]) { d2[i] = d1[i]; d1[i] = s; i1[i] = ng; }
                else if (s < d2[i]) d2[i] = s;
            }
        }
    }
    #pragma unroll
    for (int off = 16; off <= 32; off <<= 1) {
        #pragma unroll
        for (int i = 0; i < 4; ++i) {
            float od1 = __shfl_xor(d1[i], off);
            int   oi1 = __shfl_xor(i1[i], off);
            float od2 = __shfl_xor(d2[i], off);
            float nd2 = fminf(fminf(d2[i], od2), fmaxf(d1[i], od1));
            bool take = (od1 < d1[i]) || (od1 == d1[i] && oi1 < i1[i]);
            if (take) { d1[i] = od1; i1[i] = oi1; }
            d2[i] = nd2;
        }
    }
    int w = t >> 6;
    if ((t & 63) < 16) {
        #pragma unroll
        for (int i = 0; i < 4; ++i) {
            rd1[w][(tq << 2) + i] = d1[i];
            ri1[w][(tq << 2) + i] = i1[i];
            rd2[w][(tq << 2) + i] = d2[i];
        }
    }
    __syncthreads();
    if (t < 64) {
        float bd1 = rd1[0][t]; int bi1 = ri1[0][t]; float bd2 = rd2[0][t];
        #pragma unroll
        for (int ww = 1; ww < 4; ++ww) {
            float od1 = rd1[ww][t]; int oi1 = ri1[ww][t]; float od2 = rd2[ww][t];
            float nd2 = fminf(fminf(bd2, od2), fmaxf(bd1, od1));
            if (od1 < bd1 || (od1 == bd1 && oi1 < bi1)) { bd1 = od1; bi1 = oi1; }
            bd2 = nd2;
        }
        int l = l0 + t;
        ws_idx[l] = bi1;
        out_idxf[l] = (float)bi1;
        if (bd2 - bd1 < TAU) {
            int pos = atomicAdd(flag_cnt, 1);
            flag_list[pos] = l;
        } else {
            used[bi1] = 1.0f;
        }
    }
}

// ---------------- K_refine: fp64-exact argmin (r8-proven) + outq row patch ----------------
__global__ void k_refine(const float* __restrict__ z, const float* __restrict__ emb,
                         const int* __restrict__ flag_cnt, const int* __restrict__ flag_list,
                         int* __restrict__ ws_idx, float* __restrict__ out_idxf,
                         float* __restrict__ used, float* __restrict__ outq)
{
    __shared__ float zrow[Dm];
    __shared__ double sd[256];
    __shared__ int    si[256];
    int nf = *flag_cnt;
    for (int fi = blockIdx.x; fi < nf; fi += gridDim.x) {
        int l = flag_list[fi];
        int b = l >> 10, p = l & 1023;
        const float* zq = z + (size_t)b * (Dm * HW) + p;
        __syncthreads();
        for (int c = threadIdx.x; c < Dm; c += blockDim.x) zrow[c] = zq[(size_t)c * HW];
        __syncthreads();
        double bd = DBL_MAX; int bi = 0;
        for (int nb = 0; nb < NE / 256; ++nb) {
            int n = nb * 256 + threadIdx.x;
            const float* er = emb + (size_t)n * Dm;
            double dt0 = 0.0, dt1 = 0.0, dt2 = 0.0, dt3 = 0.0;
            double nm0 = 0.0, nm1 = 0.0, nm2 = 0.0, nm3 = 0.0;
            for (int c = 0; c < Dm; c += 4) {
                double e0 = er[c], e1 = er[c + 1], e2 = er[c + 2], e3 = er[c + 3];
                dt0 += e0 * (double)zrow[c];     nm0 += e0 * e0;
                dt1 += e1 * (double)zrow[c + 1]; nm1 += e1 * e1;
                dt2 += e2 * (double)zrow[c + 2]; nm2 += e2 * e2;
                dt3 += e3 * (double)zrow[c + 3]; nm3 += e3 * e3;
            }
            double s = (nm0 + nm1) + (nm2 + nm3) - 2.0 * ((dt0 + dt1) + (dt2 + dt3));
            if (s < bd) { bd = s; bi = n; }
        }
        sd[threadIdx.x] = bd; si[threadIdx.x] = bi;
        __syncthreads();
        for (int st = 128; st; st >>= 1) {
            if (threadIdx.x < (unsigned)st) {
                double od = sd[threadIdx.x + st]; int oi = si[threadIdx.x + st];
                if (od < sd[threadIdx.x] || (od == sd[threadIdx.x] && oi < si[threadIdx.x])) {
                    sd[threadIdx.x] = od; si[threadIdx.x] = oi;
                }
            }
            __syncthreads();
        }
        if (threadIdx.x == 0) {
            ws_idx[l] = si[0];
            out_idxf[l] = (float)si[0];
            used[si[0]] = 1.0f;
        }
        __syncthreads();
        // patch the quantized output row with the exact pick
        int bi0 = si[0];
        int c = threadIdx.x;
        outq[(size_t)b * (Dm * HW) + (size_t)c * HW + p] = emb[(size_t)bi0 * Dm + c];
        __syncthreads();
    }
}

// ---------------- gather (tier 2, post-refine) ----------------
__global__ __launch_bounds__(256) void k_gather(
    const float* __restrict__ emb, const int* __restrict__ ws_idx,
    float* __restrict__ outq)
{
    __shared__ int sidx[64];
    __shared__ float eldT[Dm][65];
    const int t = threadIdx.x;
    const int l0 = blockIdx.x * 64;
    const int b = l0 >> 10, p0 = l0 & 1023;
    if (t < 64) sidx[t] = ws_idx[l0 + t];
    __syncthreads();
    int w = t >> 6, lane = t & 63;
    for (int r = 0; r < 16; ++r) {
        int q = r * 4 + w;
        const float4 v = *reinterpret_cast<const float4*>(emb + (size_t)sidx[q] * Dm + lane * 4);
        eldT[lane * 4 + 0][q] = v.x; eldT[lane * 4 + 1][q] = v.y;
        eldT[lane * 4 + 2][q] = v.z; eldT[lane * 4 + 3][q] = v.w;
    }
    __syncthreads();
    const size_t obase = (size_t)b * (Dm * HW) + p0 + lane;
    #pragma unroll 4
    for (int it = 0; it < 64; ++it) {
        int c = w * 64 + it;
        outq[obase + (size_t)c * HW] = eldT[c][lane];
    }
}

// ---------------- fallback gather+loss (tier 3) ----------------
__global__ __launch_bounds__(256) void k_gather_loss(
    const float* __restrict__ z, const float* __restrict__ emb,
    const int* __restrict__ ws_idx, float* __restrict__ outq,
    float* __restrict__ partials)
{
    __shared__ int sidx[64];
    __shared__ float eldT[Dm][65];
    __shared__ float wsum[4];
    const int t = threadIdx.x;
    const int l0 = blockIdx.x * 64;
    const int b = l0 >> 10, p0 = l0 & 1023;
    if (t < 64) sidx[t] = ws_idx[l0 + t];
    __syncthreads();
    int w = t >> 6, lane = t & 63;
    for (int r = 0; r < 16; ++r) {
        int q = r * 4 + w;
        const float4 v = *reinterpret_cast<const float4*>(emb + (size_t)sidx[q] * Dm + lane * 4);
        eldT[lane * 4 + 0][q] = v.x; eldT[lane * 4 + 1][q] = v.y;
        eldT[lane * 4 + 2][q] = v.z; eldT[lane * 4 + 3][q] = v.w;
    }
    __syncthreads();
    float ls = 0.f;
    const size_t obase = (size_t)b * (Dm * HW) + p0 + lane;
    for (int it = 0; it < 64; ++it) {
        int c = w * 64 + it;
        size_t o = obase + (size_t)c * HW;
        float qv = eldT[c][lane];
        float zv = z[o];
        outq[o] = qv;
        float df = qv - zv;
        ls = fmaf(df, df, ls);
    }
    #pragma unroll
    for (int off = 32; off; off >>= 1) ls += __shfl_xor(ls, off);
    if (lane == 0) wsum[w] = ls;
    __syncthreads();
    if (t == 0) partials[blockIdx.x] = wsum[0] + wsum[1] + wsum[2] + wsum[3];
}

// ---------------- final: loss = (Sum||z||^2 + Sum d1)/count, used count ----------------
__global__ void k_final(const float* __restrict__ zn_part, const float* __restrict__ d1_part,
                        int nd1, const float* __restrict__ used,
                        float* __restrict__ out_loss, float* __restrict__ out_used)
{
    __shared__ double s1[256];
    __shared__ float  s2[256];
    int t = threadIdx.x;
    double a = 0.0;
    for (int i = t; i < 1024; i += 256) a += (double)zn_part[i];
    for (int i = t; i < nd1; i += 256) a += (double)d1_part[i];
    float u = 0.f;
    for (int i = t; i < NE; i += 256) u += used[i];
    s1[t] = a; s2[t] = u;
    __syncthreads();
    for (int st = 128; st; st >>= 1) {
        if (t < st) { s1[t] += s1[t + st]; s2[t] += s2[t + st]; }
        __syncthreads();
    }
    if (t == 0) { *out_loss = (float)(s1[0] / 8388608.0); *out_used = s2[0]; }
}

// ---------------- fallback final ----------------
__global__ void k_final_fb(const float* __restrict__ partials, const float* __restrict__ used,
                           float* __restrict__ out_loss, float* __restrict__ out_used)
{
    __shared__ float s1[256], s2[256];
    int t = threadIdx.x;
    float a = partials[t] + partials[t + 256];
    float u = 0.f;
    for (int i = t; i < NE; i += 256) u += used[i];
    s1[t] = a; s2[t] = u;
    __syncthreads();
    for (int st = 128; st; st >>= 1) {
        if (t < st) { s1[t] += s1[t + st]; s2[t] += s2[t + st]; }
        __syncthreads();
    }
    if (t == 0) { *out_loss = s1[0] / 8388608.f; *out_used = s2[0]; }
}

extern "C" void kernel_launch(void* const* d_in, const int* in_sizes, int n_in,
                              void* d_out, int out_size, void* d_ws, size_t ws_size,
                              hipStream_t stream) {
    const float* z   = (const float*)d_in[0];
    const float* emb = (const float*)d_in[1];
    float* out      = (float*)d_out;
    float* outq     = out;
    float* out_loss = out + QOFF;
    float* out_idxf = out + QOFF + 1;
    float* out_used = out + QOFF + 1 + L_TOT;

    float* ws       = (float*)d_ws;
    float* enorm    = ws;                         // [0, 2048)
    float* used     = ws + 2048;                  // [2048, 4096)
    float* zn_part  = ws + 4096;                  // [4096, 5120)
    float* d1_part  = ws + 5120;                  // [5120, 5632)  512
    int*   flag_cnt = (int*)(ws + 5632);          // 1 (+pad)
    int*   ws_idx   = (int*)(ws + 5888);          // 32768
    int*   flag_list= (int*)(ws + 5888 + L_TOT);  // 32768 -> ends 71424

    // tier-1 partials in ws (avoids outq read/write race in fused k_mg)
    float* pd1w = ws + 71680;                     // 65536
    float* pd2w = ws + 137216;                    // 65536
    int*   pi1w = (int*)(ws + 202752);            // 65536 -> ends 268288 floats

    size_t bf_bytes = 2ull * (NE + L_TOT) * Dm * sizeof(unsigned short);  // 35651584
    size_t need_t1 = 268288ull * 4 + bf_bytes;    // ~36.7 MB
    size_t need_t2 = 71680ull * 4 + bf_bytes;     // ~35.9 MB

    if (ws_size >= need_t1) {
        unsigned short* e_hi = (unsigned short*)(ws + 268288);
        unsigned short* e_lo = e_hi + (size_t)NE * Dm;
        unsigned short* z_hi = e_lo + (size_t)NE * Dm;
        unsigned short* z_lo = z_hi + (size_t)L_TOT * Dm;
        k_split<<<1024, 256, 0, stream>>>(z, emb, z_hi, z_lo, e_hi, e_lo,
                                          enorm, zn_part, used, flag_cnt);
        k_score2<<<512, 512, 0, stream>>>(z_hi, z_lo, e_hi, e_lo, enorm, pd1w, pd2w, pi1w);
        k_mg<<<L_TOT / 64, 256, 0, stream>>>(pd1w, pd2w, pi1w, emb, ws_idx, out_idxf,
                                             used, flag_cnt, flag_list, d1_part, outq);
        k_refine<<<256, 256, 0, stream>>>(z, emb, flag_cnt, flag_list, ws_idx, out_idxf,
                                          used, outq);
        k_final<<<1, 256, 0, stream>>>(zn_part, d1_part, 512, used, out_loss, out_used);
    } else if (ws_size >= need_t2) {
        unsigned short* e_hi = (unsigned short*)(ws + 71680);
        unsigned short* e_lo = e_hi + (size_t)NE * Dm;
        unsigned short* z_hi = e_lo + (size_t)NE * Dm;
        unsigned short* z_lo = z_hi + (size_t)L_TOT * Dm;
        float* pd1 = outq;
        float* pd2 = outq + 2 * L_TOT;
        int*   pi1 = (int*)(outq + 4 * L_TOT);
        k_split<<<1024, 256, 0, stream>>>(z, emb, z_hi, z_lo, e_hi, e_lo,
                                          enorm, zn_part, used, flag_cnt);
        k_score2<<<512, 512, 0, stream>>>(z_hi, z_lo, e_hi, e_lo, enorm, pd1, pd2, pi1);
        k_merge<<<L_TOT / 256, 256, 0, stream>>>(pd1, pd2, pi1, ws_idx, out_idxf, used,
                                                 flag_cnt, flag_list, d1_part);
        k_refine<<<256, 256, 0, stream>>>(z, emb, flag_cnt, flag_list, ws_idx, out_idxf,
                                          used, outq);
        k_gather<<<L_TOT / 64, 256, 0, stream>>>(emb, ws_idx, outq);
        k_final<<<1, 256, 0, stream>>>(zn_part, d1_part, 128, used, out_loss, out_used);
    } else {
        hipMemsetAsync(used, 0, (size_t)3584 * 4, stream);
        k_enorm<<<NE / 4, 256, 0, stream>>>(emb, enorm);
        k_argmin_f32<<<L_TOT / BM, 256, 0, stream>>>(z, emb, enorm, ws_idx, out_idxf, used,
                                                     flag_cnt, flag_list);
        k_refine<<<256, 256, 0, stream>>>(z, emb, flag_cnt, flag_list, ws_idx, out_idxf,
                                          used, outq);
        k_gather_loss<<<L_TOT / 64, 256, 0, stream>>>(z, emb, ws_idx, outq, zn_part);
        k_final_fb<<<1, 256, 0, stream>>>(zn_part, used, out_loss, out_used);
    }
}

// Round 11
// 234.951 us; speedup vs baseline: 1.7537x; 1.0252x over previous
//
#include <hip/hip_runtime.h>
#include <cfloat>

#define Dm 256
#define HW 1024
#define NE 2048
#define L_TOT 32768
#define QOFF 8388608   // B*C*H*W
#define TAU 0.01f

typedef __attribute__((ext_vector_type(8))) short bf16x8;
typedef __attribute__((ext_vector_type(4))) float f32x4;
typedef const __attribute__((address_space(1))) unsigned int* as1_u32p;
typedef __attribute__((address_space(3))) unsigned int* as3_u32p;

#define GLL(gp, lp) __builtin_amdgcn_global_load_lds((as1_u32p)(gp), (as3_u32p)(lp), 16, 0, 0)

__device__ __forceinline__ unsigned short f2bf(float x) {
    unsigned u = __float_as_uint(x);
    unsigned r = (u + 0x7fffu + ((u >> 16) & 1u)) >> 16;
    return (unsigned short)r;
}
__device__ __forceinline__ float bf2f(unsigned short h) {
    return __uint_as_float(((unsigned)h) << 16);
}

// ---------------- K1 (fallback only): code norms ----------------
__global__ void k_enorm(const float* __restrict__ emb, float* __restrict__ enorm) {
    int w = threadIdx.x >> 6, lane = threadIdx.x & 63;
    int n = blockIdx.x * 4 + w;
    const float4 v = *reinterpret_cast<const float4*>(emb + (size_t)n * Dm + lane * 4);
    double s = (double)v.x * v.x + (double)v.y * v.y + (double)v.z * v.z + (double)v.w * v.w;
    #pragma unroll
    for (int off = 32; off; off >>= 1) s += __shfl_xor(s, off);
    if (lane == 0) enorm[n] = (float)s;
}

// ---------------- fused: split Z (transpose) + split E + norms + ws zeroing ----------------
__global__ __launch_bounds__(256) void k_split(
    const float* __restrict__ z, const float* __restrict__ emb,
    unsigned short* __restrict__ z_hi, unsigned short* __restrict__ z_lo,
    unsigned short* __restrict__ e_hi, unsigned short* __restrict__ e_lo,
    float* __restrict__ enorm, float* __restrict__ zn_part,
    float* __restrict__ used, int* __restrict__ flag_cnt)
{
    __shared__ unsigned short zh[32][260];
    __shared__ unsigned short zl[32][260];
    __shared__ double zsum[4];
    const int t = threadIdx.x;
    const int w = t >> 6, lane = t & 63;

    // ws zeroing (replaces memset launch)
    if (blockIdx.x >= 16 && blockIdx.x < 24) used[(blockIdx.x - 16) * 256 + t] = 0.f;
    if (blockIdx.x == 24 && t == 0) *flag_cnt = 0;

    // fused E-split: waves 0,1 each handle one emb row (2048 rows / 1024 blocks)
    if (w < 2) {
        int n = blockIdx.x * 2 + w;
        const float4 v = *reinterpret_cast<const float4*>(emb + (size_t)n * Dm + lane * 4);
        float vv[4] = { v.x, v.y, v.z, v.w };
        double s = (double)v.x * v.x + (double)v.y * v.y + (double)v.z * v.z + (double)v.w * v.w;
        #pragma unroll
        for (int off = 32; off; off >>= 1) s += __shfl_xor(s, off);
        if (lane == 0) enorm[n] = (float)s;
        ushort4 h4, l4;
        unsigned short* hp = (unsigned short*)&h4;
        unsigned short* lp = (unsigned short*)&l4;
        #pragma unroll
        for (int j = 0; j < 4; ++j) {
            unsigned short h = f2bf(vv[j]);
            hp[j] = h;
            lp[j] = f2bf(vv[j] - bf2f(h));
        }
        *reinterpret_cast<ushort4*>(e_hi + (size_t)n * Dm + lane * 4) = h4;
        *reinterpret_cast<ushort4*>(e_lo + (size_t)n * Dm + lane * 4) = l4;
    }

    // Z split+transpose + ||z||^2 partial
    const int b  = blockIdx.x >> 5;
    const int p0 = (blockIdx.x & 31) * 32;
    const int pp = t & 31, cb = t >> 5;
    const float* zb = z + (size_t)b * (Dm * HW) + p0 + pp;
    float zs = 0.f;
    for (int ci = 0; ci < 32; ++ci) {
        int c = ci * 8 + cb;
        float x = zb[(size_t)c * HW];
        zs = fmaf(x, x, zs);
        unsigned short h = f2bf(x);
        zh[pp][c] = h;
        zl[pp][c] = f2bf(x - bf2f(h));
    }
    double d = zs;
    #pragma unroll
    for (int off = 32; off; off >>= 1) d += __shfl_xor(d, off);
    if ((t & 63) == 0) zsum[w] = d;
    __syncthreads();
    if (t == 0) zn_part[blockIdx.x] = (float)(zsum[0] + zsum[1] + zsum[2] + zsum[3]);
    const int l0 = b * 1024 + p0;
    #pragma unroll
    for (int r = 0; r < 8; ++r) {
        int id = r * 256 + t;
        int row = id >> 6, ch = id & 63;
        *reinterpret_cast<ushort4*>(z_hi + (size_t)(l0 + row) * Dm + ch * 4) =
            *reinterpret_cast<ushort4*>(&zh[row][ch * 4]);
        *reinterpret_cast<ushort4*>(z_lo + (size_t)(l0 + row) * Dm + ch * 4) =
            *reinterpret_cast<ushort4*>(&zl[row][ch * 4]);
    }
}

// ---------------- K2: bf16-split score GEMM + top-2 argmin ----------------
// r10-proven structure; single variable change: VALU diet on staging only.
// GLL issue ORDER (A,B,A,B), addresses, barriers, MFMA sequence identical to r10.
// Diet: per-thread byte offsets hoisted; division-free (pnt,pkt) carried counters.
__global__ __launch_bounds__(512, 4) void k_score2(
    const unsigned short* __restrict__ z_hi, const unsigned short* __restrict__ z_lo,
    const unsigned short* __restrict__ e_hi, const unsigned short* __restrict__ e_lo,
    const float* __restrict__ enorm,
    float* __restrict__ pd1, float* __restrict__ pd2, int* __restrict__ pi1)
{
    __shared__ unsigned short lds[2][2][128 * 64];   // [buf][A=0/B=1][row*64+k]

    const int t    = threadIdx.x;
    const int lane = t & 63, w = t >> 6;
    const int wm = w >> 2, wn = w & 3;
    const int c15 = lane & 15, g4 = lane >> 4;

    const int bx = blockIdx.x;
    const int wg = (bx & 7) * 64 + (bx >> 3);
    const int mi = wg >> 1, ni = wg & 1;
    const int l0 = mi * 128;
    const int nbase = ni * 1024;

    // hoisted staging descriptors (same addresses as r10's stage lambda):
    // id = r*512+t -> row = r*64 + (t>>3), ch = t&7, chg = ch ^ (row&7) = (t&7)^((t>>3)&7)
    const int srow = t >> 3;
    const int chg  = (t & 7) ^ (srow & 7);
    const int aoff0 = (l0 + srow) * Dm + chg * 8;      // A, r=0
    const int aoff1 = aoff0 + 64 * Dm;                 // A, r=1
    const int bbase = srow * Dm + chg * 8 + nbase * Dm;
    const int ld0 = t * 8, ld1 = t * 8 + 4096;

    auto stage = [&](int buf, const unsigned short* As, const unsigned short* Bs,
                     int ntoff, int k0) {
        // identical issue order to r10: r=0 {A,B}, r=1 {A,B}
        GLL(As + aoff0 + k0,                 &lds[buf][0][ld0]);
        GLL(Bs + bbase + ntoff + k0,         &lds[buf][1][ld0]);
        GLL(As + aoff1 + k0,                 &lds[buf][0][ld1]);
        GLL(Bs + bbase + ntoff + 64 * Dm + k0, &lds[buf][1][ld1]);
    };

    float d1[4][4], d2[4][4]; int i1[4][4];
    #pragma unroll
    for (int m = 0; m < 4; ++m)
        #pragma unroll
        for (int r = 0; r < 4; ++r) { d1[m][r] = 3.4e38f; d2[m][r] = 3.4e38f; i1[m][r] = 0; }

    stage(0, z_hi, e_hi, 0, 0);
    __syncthreads();

    int cur = 0, it = 0;
    int pnt = 0, pkt = 1;   // (nt, kt) indices of the next chunk to stage
    for (int nt = 0; nt < 8; ++nt) {
        f32x4 acc[4][2];
        #pragma unroll
        for (int m = 0; m < 4; ++m)
            #pragma unroll
            for (int n = 0; n < 2; ++n) acc[m][n] = (f32x4){0.f, 0.f, 0.f, 0.f};

        for (int kt = 0; kt < 12; ++kt, ++it) {
            if (it + 1 < 96) {
                const int nterm = pkt >> 2, nkc = pkt & 3;
                const unsigned short* As = (nterm == 1) ? z_lo : z_hi;
                const unsigned short* Bs = (nterm == 2) ? e_lo : e_hi;
                stage(cur ^ 1, As, Bs, pnt << 15, nkc << 6);
                if (++pkt == 12) { pkt = 0; ++pnt; }
            }
            const unsigned short* Ab = &lds[cur][0][0];
            const unsigned short* Bb = &lds[cur][1][0];
            #pragma unroll
            for (int ks = 0; ks < 2; ++ks) {
                bf16x8 af[4], bfr[2];
                #pragma unroll
                for (int m = 0; m < 4; ++m) {
                    int row = wm * 64 + m * 16 + c15;
                    int cc  = ks * 4 + g4;
                    af[m] = *reinterpret_cast<const bf16x8*>(
                        &Ab[row * 64 + ((cc ^ (row & 7)) << 3)]);
                }
                #pragma unroll
                for (int n = 0; n < 2; ++n) {
                    int row = wn * 32 + n * 16 + c15;
                    int cc  = ks * 4 + g4;
                    bfr[n] = *reinterpret_cast<const bf16x8*>(
                        &Bb[row * 64 + ((cc ^ (row & 7)) << 3)]);
                }
                __builtin_amdgcn_s_setprio(1);
                #pragma unroll
                for (int m = 0; m < 4; ++m)
                    #pragma unroll
                    for (int n = 0; n < 2; ++n)
                        acc[m][n] = __builtin_amdgcn_mfma_f32_16x16x32_bf16(
                            af[m], bfr[n], acc[m][n], 0, 0, 0);
                __builtin_amdgcn_s_setprio(0);
            }
            __syncthreads();
            cur ^= 1;
        }
        int n0 = nbase + nt * 128;
        #pragma unroll
        for (int n = 0; n < 2; ++n) {
            int ng = n0 + wn * 32 + n * 16 + c15;
            float en = enorm[ng];
            #pragma unroll
            for (int m = 0; m < 4; ++m)
                #pragma unroll
                for (int r = 0; r < 4; ++r) {
                    float s = fmaf(-2.f, acc[m][n][r], en);
                    if (s < d1[m][r]) { d2[m][r] = d1[m][r]; d1[m][r] = s; i1[m][r] = ng; }
                    else if (s < d2[m][r]) d2[m][r] = s;
                }
        }
    }

    #pragma unroll
    for (int off = 1; off <= 8; off <<= 1) {
        #pragma unroll
        for (int m = 0; m < 4; ++m)
            #pragma unroll
            for (int r = 0; r < 4; ++r) {
                float od1 = __shfl_xor(d1[m][r], off);
                int   oi1 = __shfl_xor(i1[m][r], off);
                float od2 = __shfl_xor(d2[m][r], off);
                float nd2 = fminf(fminf(d2[m][r], od2), fmaxf(d1[m][r], od1));
                if (od1 < d1[m][r] || (od1 == d1[m][r] && oi1 < i1[m][r])) {
                    d1[m][r] = od1; i1[m][r] = oi1;
                }
                d2[m][r] = nd2;
            }
    }

    float* rs1 = (float*)&lds[0][0][0];
    float* rs2 = rs1 + 3 * 128;
    int*   ri  = (int*)(rs2 + 3 * 128);
    if (wn > 0 && c15 == 0) {
        int s = wn - 1;
        #pragma unroll
        for (int m = 0; m < 4; ++m)
            #pragma unroll
            for (int r = 0; r < 4; ++r) {
                int q = wm * 64 + m * 16 + g4 * 4 + r;
                rs1[s * 128 + q] = d1[m][r];
                rs2[s * 128 + q] = d2[m][r];
                ri [s * 128 + q] = i1[m][r];
            }
    }
    __syncthreads();
    if (wn == 0 && c15 == 0) {
        #pragma unroll
        for (int m = 0; m < 4; ++m)
            #pragma unroll
            for (int r = 0; r < 4; ++r) {
                int q = wm * 64 + m * 16 + g4 * 4 + r;
                float bd1 = d1[m][r], bd2 = d2[m][r]; int bi1 = i1[m][r];
                #pragma unroll
                for (int s = 0; s < 3; ++s) {
                    float od1 = rs1[s * 128 + q], od2 = rs2[s * 128 + q];
                    int   oi1 = ri [s * 128 + q];
                    float nd2 = fminf(fminf(bd2, od2), fmaxf(bd1, od1));
                    if (od1 < bd1 || (od1 == bd1 && oi1 < bi1)) { bd1 = od1; bi1 = oi1; }
                    bd2 = nd2;
                }
                int gq = l0 + q;
                pd1[ni * L_TOT + gq] = bd1;
                pd2[ni * L_TOT + gq] = bd2;
                pi1[ni * L_TOT + gq] = bi1;
            }
    }
}

// ---------------- fused merge + gather (tier 1) ----------------
__global__ __launch_bounds__(256) void k_mg(
    const float* __restrict__ pd1, const float* __restrict__ pd2,
    const int* __restrict__ pi1, const float* __restrict__ emb,
    int* __restrict__ ws_idx, float* __restrict__ out_idxf,
    float* __restrict__ used, int* __restrict__ flag_cnt,
    int* __restrict__ flag_list, float* __restrict__ d1_part,
    float* __restrict__ outq)
{
    __shared__ int sidx[64];
    __shared__ float eldT[Dm][65];
    const int t = threadIdx.x;
    const int l0 = blockIdx.x * 64;
    const int b = l0 >> 10, p0 = l0 & 1023;

    if (t < 64) {
        int gq = l0 + t;
        float d1 = pd1[gq], d2 = pd2[gq]; int i1 = pi1[gq];
        float od1 = pd1[L_TOT + gq], od2 = pd2[L_TOT + gq];
        int   oi1 = pi1[L_TOT + gq];
        float nd2 = fminf(fminf(d2, od2), fmaxf(d1, od1));
        if (od1 < d1 || (od1 == d1 && oi1 < i1)) { d1 = od1; i1 = oi1; }
        d2 = nd2;
        ws_idx[gq] = i1;
        out_idxf[gq] = (float)i1;
        if (d2 - d1 < TAU) {
            int pos = atomicAdd(flag_cnt, 1);
            flag_list[pos] = gq;
        } else {
            used[i1] = 1.0f;
        }
        sidx[t] = i1;
        float s = d1;
        #pragma unroll
        for (int off = 32; off; off >>= 1) s += __shfl_xor(s, off);
        if (t == 0) d1_part[blockIdx.x] = s;
    }
    __syncthreads();

    int w = t >> 6, lane = t & 63;
    for (int r = 0; r < 16; ++r) {
        int q = r * 4 + w;
        const float4 v = *reinterpret_cast<const float4*>(emb + (size_t)sidx[q] * Dm + lane * 4);
        eldT[lane * 4 + 0][q] = v.x; eldT[lane * 4 + 1][q] = v.y;
        eldT[lane * 4 + 2][q] = v.z; eldT[lane * 4 + 3][q] = v.w;
    }
    __syncthreads();
    const size_t obase = (size_t)b * (Dm * HW) + p0 + lane;
    #pragma unroll 4
    for (int it = 0; it < 64; ++it) {
        int c = w * 64 + it;
        outq[obase + (size_t)c * HW] = eldT[c][lane];
    }
}

// ---------------- merge only (tier 2, r7-proven) ----------------
__global__ __launch_bounds__(256) void k_merge(
    const float* __restrict__ pd1, const float* __restrict__ pd2,
    const int* __restrict__ pi1, int* __restrict__ ws_idx,
    float* __restrict__ out_idxf, float* __restrict__ used,
    int* __restrict__ flag_cnt, int* __restrict__ flag_list,
    float* __restrict__ d1_part)
{
    __shared__ float sdl[256];
    int tt = threadIdx.x;
    int gq = blockIdx.x * 256 + tt;
    float d1 = pd1[gq], d2 = pd2[gq]; int i1 = pi1[gq];
    {
        float od1 = pd1[L_TOT + gq], od2 = pd2[L_TOT + gq];
        int   oi1 = pi1[L_TOT + gq];
        float nd2 = fminf(fminf(d2, od2), fmaxf(d1, od1));
        if (od1 < d1 || (od1 == d1 && oi1 < i1)) { d1 = od1; i1 = oi1; }
        d2 = nd2;
    }
    ws_idx[gq] = i1;
    out_idxf[gq] = (float)i1;
    if (d2 - d1 < TAU) {
        int pos = atomicAdd(flag_cnt, 1);
        flag_list[pos] = gq;
    } else {
        used[i1] = 1.0f;
    }
    sdl[tt] = d1;
    __syncthreads();
    for (int st = 128; st; st >>= 1) {
        if (tt < st) sdl[tt] += sdl[tt + st];
        __syncthreads();
    }
    if (tt == 0) d1_part[blockIdx.x] = sdl[0];
}

// ---------------- fallback fp32 argmin (round-1 proven) ----------------
#define BM 64
#define BN 128
#define BK 64
__global__ __launch_bounds__(256, 2) void k_argmin_f32(
    const float* __restrict__ z, const float* __restrict__ emb,
    const float* __restrict__ enorm, int* __restrict__ ws_idx,
    float* __restrict__ out_idxf, float* __restrict__ used,
    int* __restrict__ flag_cnt, int* __restrict__ flag_list)
{
    __shared__ float zl[BK][BM];
    __shared__ float el[BK][BN + 4];
    __shared__ float rd1[4][64];
    __shared__ int   ri1[4][64];
    __shared__ float rd2[4][64];

    const int t  = threadIdx.x;
    const int tq = t & 15;
    const int tn = t >> 4;
    const int l0 = blockIdx.x * BM;
    const int b  = l0 >> 10, p0 = l0 & 1023;
    const float* zb = z + (size_t)b * (Dm * HW) + p0;

    float d1[4], d2[4]; int i1[4];
    #pragma unroll
    for (int i = 0; i < 4; ++i) { d1[i] = FLT_MAX; d2[i] = FLT_MAX; i1[i] = 0; }

    for (int nt = 0; nt < NE / BN; ++nt) {
        const int n0 = nt * BN;
        float acc[4][8];
        #pragma unroll
        for (int i = 0; i < 4; ++i)
            #pragma unroll
            for (int j = 0; j < 8; ++j) acc[i][j] = 0.f;

        for (int kc = 0; kc < Dm / BK; ++kc) {
            __syncthreads();
            #pragma unroll
            for (int r = 0; r < 4; ++r) {
                int f = r * 256 + t;
                int kk = f >> 4, q4 = (f & 15) << 2;
                float4 v = *reinterpret_cast<const float4*>(zb + (size_t)(kc * BK + kk) * HW + q4);
                *reinterpret_cast<float4*>(&zl[kk][q4]) = v;
            }
            #pragma unroll
            for (int r = 0; r < 8; ++r) {
                int f = r * 256 + t;
                int n = f >> 4, k4 = (f & 15) << 2;
                float4 v = *reinterpret_cast<const float4*>(emb + (size_t)(n0 + n) * Dm + kc * BK + k4);
                el[k4 + 0][n] = v.x; el[k4 + 1][n] = v.y;
                el[k4 + 2][n] = v.z; el[k4 + 3][n] = v.w;
            }
            __syncthreads();
            #pragma unroll 4
            for (int kk = 0; kk < BK; ++kk) {
                float4 zf = *reinterpret_cast<const float4*>(&zl[kk][tq << 2]);
                float4 e0 = *reinterpret_cast<const float4*>(&el[kk][tn << 3]);
                float4 e1 = *reinterpret_cast<const float4*>(&el[kk][(tn << 3) + 4]);
                float zr[4] = { zf.x, zf.y, zf.z, zf.w };
                float er[8] = { e0.x, e0.y, e0.z, e0.w, e1.x, e1.y, e1.z, e1.w };
                #pragma unroll
                for (int i = 0; i < 4; ++i)
                    #pragma unroll
                    for (int j = 0; j < 8; ++j)
                        acc[i][j] = fmaf(zr[i], er[j], acc[i][j]);
            }
        }
        #pragma unroll
        for (int j = 0; j < 8; ++j) {
            int ng = n0 + (tn << 3) + j;
            float en = enorm[ng];
            #pragma unroll
            for (int i = 0; i < 4; ++i) {
                float s = fmaf(-2.f, acc[i][j], en);
                if (s < d1[i]) { d2[i] = d1[i]; d1[i] = s; i1[i] = ng; }
                else if (s < d2[i]) d2[i] = s;
            }
        }
    }
    #pragma unroll
    for (int off = 16; off <= 32; off <<= 1) {
        #pragma unroll
        for (int i = 0; i < 4; ++i) {
            float od1 = __shfl_xor(d1[i], off);
            int   oi1 = __shfl_xor(i1[i], off);
            float od2 = __shfl_xor(d2[i], off);
            float nd2 = fminf(fminf(d2[i], od2), fmaxf(d1[i], od1));
            bool take = (od1 < d1[i]) || (od1 == d1[i] && oi1 < i1[i]);
            if (take) { d1[i] = od1; i1[i] = oi1; }
            d2[i] = nd2;
        }
    }
    int w = t >> 6;
    if ((t & 63) < 16) {
        #pragma unroll
        for (int i = 0; i < 4; ++i) {
            rd1[w][(tq << 2) + i] = d1[i];
            ri1[w][(tq << 2) + i] = i1[i];
            rd2[w][(tq << 2) + i] = d2[i];
        }
    }
    __syncthreads();
    if (t < 64) {
        float bd1 = rd1[0][t]; int bi1 = ri1[0][t]; float bd2 = rd2[0][t];
        #pragma unroll
        for (int ww = 1; ww < 4; ++ww) {
            float od1 = rd1[ww][t]; int oi1 = ri1[ww][t]; float od2 = rd2[ww][t];
            float nd2 = fminf(fminf(bd2, od2), fmaxf(bd1, od1));
            if (od1 < bd1 || (od1 == bd1 && oi1 < bi1)) { bd1 = od1; bi1 = oi1; }
            bd2 = nd2;
        }
        int l = l0 + t;
        ws_idx[l] = bi1;
        out_idxf[l] = (float)bi1;
        if (bd2 - bd1 < TAU) {
            int pos = atomicAdd(flag_cnt, 1);
            flag_list[pos] = l;
        } else {
            used[bi1] = 1.0f;
        }
    }
}

// ---------------- K_refine: fp64-exact argmin (r8-proven) + outq row patch ----------------
__global__ void k_refine(const float* __restrict__ z, const float* __restrict__ emb,
                         const int* __restrict__ flag_cnt, const int* __restrict__ flag_list,
                         int* __restrict__ ws_idx, float* __restrict__ out_idxf,
                         float* __restrict__ used, float* __restrict__ outq)
{
    __shared__ float zrow[Dm];
    __shared__ double sd[256];
    __shared__ int    si[256];
    int nf = *flag_cnt;
    for (int fi = blockIdx.x; fi < nf; fi += gridDim.x) {
        int l = flag_list[fi];
        int b = l >> 10, p = l & 1023;
        const float* zq = z + (size_t)b * (Dm * HW) + p;
        __syncthreads();
        for (int c = threadIdx.x; c < Dm; c += blockDim.x) zrow[c] = zq[(size_t)c * HW];
        __syncthreads();
        double bd = DBL_MAX; int bi = 0;
        for (int nb = 0; nb < NE / 256; ++nb) {
            int n = nb * 256 + threadIdx.x;
            const float* er = emb + (size_t)n * Dm;
            double dt0 = 0.0, dt1 = 0.0, dt2 = 0.0, dt3 = 0.0;
            double nm0 = 0.0, nm1 = 0.0, nm2 = 0.0, nm3 = 0.0;
            for (int c = 0; c < Dm; c += 4) {
                double e0 = er[c], e1 = er[c + 1], e2 = er[c + 2], e3 = er[c + 3];
                dt0 += e0 * (double)zrow[c];     nm0 += e0 * e0;
                dt1 += e1 * (double)zrow[c + 1]; nm1 += e1 * e1;
                dt2 += e2 * (double)zrow[c + 2]; nm2 += e2 * e2;
                dt3 += e3 * (double)zrow[c + 3]; nm3 += e3 * e3;
            }
            double s = (nm0 + nm1) + (nm2 + nm3) - 2.0 * ((dt0 + dt1) + (dt2 + dt3));
            if (s < bd) { bd = s; bi = n; }
        }
        sd[threadIdx.x] = bd; si[threadIdx.x] = bi;
        __syncthreads();
        for (int st = 128; st; st >>= 1) {
            if (threadIdx.x < (unsigned)st) {
                double od = sd[threadIdx.x + st]; int oi = si[threadIdx.x + st];
                if (od < sd[threadIdx.x] || (od == sd[threadIdx.x] && oi < si[threadIdx.x])) {
                    sd[threadIdx.x] = od; si[threadIdx.x] = oi;
                }
            }
            __syncthreads();
        }
        if (threadIdx.x == 0) {
            ws_idx[l] = si[0];
            out_idxf[l] = (float)si[0];
            used[si[0]] = 1.0f;
        }
        __syncthreads();
        int bi0 = si[0];
        int c = threadIdx.x;
        outq[(size_t)b * (Dm * HW) + (size_t)c * HW + p] = emb[(size_t)bi0 * Dm + c];
        __syncthreads();
    }
}

// ---------------- gather (tier 2, post-refine) ----------------
__global__ __launch_bounds__(256) void k_gather(
    const float* __restrict__ emb, const int* __restrict__ ws_idx,
    float* __restrict__ outq)
{
    __shared__ int sidx[64];
    __shared__ float eldT[Dm][65];
    const int t = threadIdx.x;
    const int l0 = blockIdx.x * 64;
    const int b = l0 >> 10, p0 = l0 & 1023;
    if (t < 64) sidx[t] = ws_idx[l0 + t];
    __syncthreads();
    int w = t >> 6, lane = t & 63;
    for (int r = 0; r < 16; ++r) {
        int q = r * 4 + w;
        const float4 v = *reinterpret_cast<const float4*>(emb + (size_t)sidx[q] * Dm + lane * 4);
        eldT[lane * 4 + 0][q] = v.x; eldT[lane * 4 + 1][q] = v.y;
        eldT[lane * 4 + 2][q] = v.z; eldT[lane * 4 + 3][q] = v.w;
    }
    __syncthreads();
    const size_t obase = (size_t)b * (Dm * HW) + p0 + lane;
    #pragma unroll 4
    for (int it = 0; it < 64; ++it) {
        int c = w * 64 + it;
        outq[obase + (size_t)c * HW] = eldT[c][lane];
    }
}

// ---------------- fallback gather+loss (tier 3) ----------------
__global__ __launch_bounds__(256) void k_gather_loss(
    const float* __restrict__ z, const float* __restrict__ emb,
    const int* __restrict__ ws_idx, float* __restrict__ outq,
    float* __restrict__ partials)
{
    __shared__ int sidx[64];
    __shared__ float eldT[Dm][65];
    __shared__ float wsum[4];
    const int t = threadIdx.x;
    const int l0 = blockIdx.x * 64;
    const int b = l0 >> 10, p0 = l0 & 1023;
    if (t < 64) sidx[t] = ws_idx[l0 + t];
    __syncthreads();
    int w = t >> 6, lane = t & 63;
    for (int r = 0; r < 16; ++r) {
        int q = r * 4 + w;
        const float4 v = *reinterpret_cast<const float4*>(emb + (size_t)sidx[q] * Dm + lane * 4);
        eldT[lane * 4 + 0][q] = v.x; eldT[lane * 4 + 1][q] = v.y;
        eldT[lane * 4 + 2][q] = v.z; eldT[lane * 4 + 3][q] = v.w;
    }
    __syncthreads();
    float ls = 0.f;
    const size_t obase = (size_t)b * (Dm * HW) + p0 + lane;
    for (int it = 0; it < 64; ++it) {
        int c = w * 64 + it;
        size_t o = obase + (size_t)c * HW;
        float qv = eldT[c][lane];
        float zv = z[o];
        outq[o] = qv;
        float df = qv - zv;
        ls = fmaf(df, df, ls);
    }
    #pragma unroll
    for (int off = 32; off; off >>= 1) ls += __shfl_xor(ls, off);
    if (lane == 0) wsum[w] = ls;
    __syncthreads();
    if (t == 0) partials[blockIdx.x] = wsum[0] + wsum[1] + wsum[2] + wsum[3];
}

// ---------------- final: loss = (Sum||z||^2 + Sum d1)/count, used count ----------------
__global__ void k_final(const float* __restrict__ zn_part, const float* __restrict__ d1_part,
                        int nd1, const float* __restrict__ used,
                        float* __restrict__ out_loss, float* __restrict__ out_used)
{
    __shared__ double s1[256];
    __shared__ float  s2[256];
    int t = threadIdx.x;
    double a = 0.0;
    for (int i = t; i < 1024; i += 256) a += (double)zn_part[i];
    for (int i = t; i < nd1; i += 256) a += (double)d1_part[i];
    float u = 0.f;
    for (int i = t; i < NE; i += 256) u += used[i];
    s1[t] = a; s2[t] = u;
    __syncthreads();
    for (int st = 128; st; st >>= 1) {
        if (t < st) { s1[t] += s1[t + st]; s2[t] += s2[t + st]; }
        __syncthreads();
    }
    if (t == 0) { *out_loss = (float)(s1[0] / 8388608.0); *out_used = s2[0]; }
}

// ---------------- fallback final ----------------
__global__ void k_final_fb(const float* __restrict__ partials, const float* __restrict__ used,
                           float* __restrict__ out_loss, float* __restrict__ out_used)
{
    __shared__ float s1[256], s2[256];
    int t = threadIdx.x;
    float a = partials[t] + partials[t + 256];
    float u = 0.f;
    for (int i = t; i < NE; i += 256) u += used[i];
    s1[t] = a; s2[t] = u;
    __syncthreads();
    for (int st = 128; st; st >>= 1) {
        if (t < st) { s1[t] += s1[t + st]; s2[t] += s2[t + st]; }
        __syncthreads();
    }
    if (t == 0) { *out_loss = s1[0] / 8388608.f; *out_used = s2[0]; }
}

extern "C" void kernel_launch(void* const* d_in, const int* in_sizes, int n_in,
                              void* d_out, int out_size, void* d_ws, size_t ws_size,
                              hipStream_t stream) {
    const float* z   = (const float*)d_in[0];
    const float* emb = (const float*)d_in[1];
    float* out      = (float*)d_out;
    float* outq     = out;
    float* out_loss = out + QOFF;
    float* out_idxf = out + QOFF + 1;
    float* out_used = out + QOFF + 1 + L_TOT;

    float* ws       = (float*)d_ws;
    float* enorm    = ws;                         // [0, 2048)
    float* used     = ws + 2048;                  // [2048, 4096)
    float* zn_part  = ws + 4096;                  // [4096, 5120)
    float* d1_part  = ws + 5120;                  // [5120, 5632)  512
    int*   flag_cnt = (int*)(ws + 5632);          // 1 (+pad)
    int*   ws_idx   = (int*)(ws + 5888);          // 32768
    int*   flag_list= (int*)(ws + 5888 + L_TOT);  // 32768 -> ends 71424

    // tier-1 partials in ws (avoids outq read/write race in fused k_mg)
    float* pd1w = ws + 71680;                     // 65536
    float* pd2w = ws + 137216;                    // 65536
    int*   pi1w = (int*)(ws + 202752);            // 65536 -> ends 268288 floats

    size_t bf_bytes = 2ull * (NE + L_TOT) * Dm * sizeof(unsigned short);  // 35651584
    size_t need_t1 = 268288ull * 4 + bf_bytes;    // ~36.7 MB
    size_t need_t2 = 71680ull * 4 + bf_bytes;     // ~35.9 MB

    if (ws_size >= need_t1) {
        unsigned short* e_hi = (unsigned short*)(ws + 268288);
        unsigned short* e_lo = e_hi + (size_t)NE * Dm;
        unsigned short* z_hi = e_lo + (size_t)NE * Dm;
        unsigned short* z_lo = z_hi + (size_t)L_TOT * Dm;
        k_split<<<1024, 256, 0, stream>>>(z, emb, z_hi, z_lo, e_hi, e_lo,
                                          enorm, zn_part, used, flag_cnt);
        k_score2<<<512, 512, 0, stream>>>(z_hi, z_lo, e_hi, e_lo, enorm, pd1w, pd2w, pi1w);
        k_mg<<<L_TOT / 64, 256, 0, stream>>>(pd1w, pd2w, pi1w, emb, ws_idx, out_idxf,
                                             used, flag_cnt, flag_list, d1_part, outq);
        k_refine<<<256, 256, 0, stream>>>(z, emb, flag_cnt, flag_list, ws_idx, out_idxf,
                                          used, outq);
        k_final<<<1, 256, 0, stream>>>(zn_part, d1_part, 512, used, out_loss, out_used);
    } else if (ws_size >= need_t2) {
        unsigned short* e_hi = (unsigned short*)(ws + 71680);
        unsigned short* e_lo = e_hi + (size_t)NE * Dm;
        unsigned short* z_hi = e_lo + (size_t)NE * Dm;
        unsigned short* z_lo = z_hi + (size_t)L_TOT * Dm;
        float* pd1 = outq;
        float* pd2 = outq + 2 * L_TOT;
        int*   pi1 = (int*)(outq + 4 * L_TOT);
        k_split<<<1024, 256, 0, stream>>>(z, emb, z_hi, z_lo, e_hi, e_lo,
                                          enorm, zn_part, used, flag_cnt);
        k_score2<<<512, 512, 0, stream>>>(z_hi, z_lo, e_hi, e_lo, enorm, pd1, pd2, pi1);
        k_merge<<<L_TOT / 256, 256, 0, stream>>>(pd1, pd2, pi1, ws_idx, out_idxf, used,
                                                 flag_cnt, flag_list, d1_part);
        k_refine<<<256, 256, 0, stream>>>(z, emb, flag_cnt, flag_list, ws_idx, out_idxf,
                                          used, outq);
        k_gather<<<L_TOT / 64, 256, 0, stream>>>(emb, ws_idx, outq);
        k_final<<<1, 256, 0, stream>>>(zn_part, d1_part, 128, used, out_loss, out_used);
    } else {
        hipMemsetAsync(used, 0, (size_t)3584 * 4, stream);
        k_enorm<<<NE / 4, 256, 0, stream>>>(emb, enorm);
        k_argmin_f32<<<L_TOT / BM, 256, 0, stream>>>(z, emb, enorm, ws_idx, out_idxf, used,
                                                     flag_cnt, flag_list);
        k_refine<<<256, 256, 0, stream>>>(z, emb, flag_cnt, flag_list, ws_idx, out_idxf,
                                          used, outq);
        k_gather_loss<<<L_TOT / 64, 256, 0, stream>>>(z, emb, ws_idx, outq, zn_part);
        k_final_fb<<<1, 256, 0, stream>>>(zn_part, used, out_loss, out_used);
    }
}

// Round 12
// 232.513 us; speedup vs baseline: 1.7721x; 1.0105x over previous
//
#include <hip/hip_runtime.h>
#include <cfloat>

#define Dm 256
#define HW 1024
#define NE 2048
#define L_TOT 32768
#define QOFF 8388608   // B*C*H*W
#define TAU 0.01f

typedef __attribute__((ext_vector_type(8))) short bf16x8;
typedef __attribute__((ext_vector_type(4))) float f32x4;
typedef const __attribute__((address_space(1))) unsigned int* as1_u32p;
typedef __attribute__((address_space(3))) unsigned int* as3_u32p;

#define GLL(gp, lp) __builtin_amdgcn_global_load_lds((as1_u32p)(gp), (as3_u32p)(lp), 16, 0, 0)

__device__ __forceinline__ unsigned short f2bf(float x) {
    unsigned u = __float_as_uint(x);
    unsigned r = (u + 0x7fffu + ((u >> 16) & 1u)) >> 16;
    return (unsigned short)r;
}
__device__ __forceinline__ float bf2f(unsigned short h) {
    return __uint_as_float(((unsigned)h) << 16);
}

// ---------------- K1 (fallback only): code norms ----------------
__global__ void k_enorm(const float* __restrict__ emb, float* __restrict__ enorm) {
    int w = threadIdx.x >> 6, lane = threadIdx.x & 63;
    int n = blockIdx.x * 4 + w;
    const float4 v = *reinterpret_cast<const float4*>(emb + (size_t)n * Dm + lane * 4);
    double s = (double)v.x * v.x + (double)v.y * v.y + (double)v.z * v.z + (double)v.w * v.w;
    #pragma unroll
    for (int off = 32; off; off >>= 1) s += __shfl_xor(s, off);
    if (lane == 0) enorm[n] = (float)s;
}

// ---------------- fused: split Z (transpose) + split E + norms + ws zeroing ----------------
__global__ __launch_bounds__(256) void k_split(
    const float* __restrict__ z, const float* __restrict__ emb,
    unsigned short* __restrict__ z_hi, unsigned short* __restrict__ z_lo,
    unsigned short* __restrict__ e_hi, unsigned short* __restrict__ e_lo,
    float* __restrict__ enorm, float* __restrict__ zn_part,
    float* __restrict__ used, int* __restrict__ flag_cnt)
{
    __shared__ unsigned short zh[32][260];
    __shared__ unsigned short zl[32][260];
    __shared__ double zsum[4];
    const int t = threadIdx.x;
    const int w = t >> 6, lane = t & 63;

    if (blockIdx.x >= 16 && blockIdx.x < 24) used[(blockIdx.x - 16) * 256 + t] = 0.f;
    if (blockIdx.x == 24 && t == 0) *flag_cnt = 0;

    if (w < 2) {
        int n = blockIdx.x * 2 + w;
        const float4 v = *reinterpret_cast<const float4*>(emb + (size_t)n * Dm + lane * 4);
        float vv[4] = { v.x, v.y, v.z, v.w };
        double s = (double)v.x * v.x + (double)v.y * v.y + (double)v.z * v.z + (double)v.w * v.w;
        #pragma unroll
        for (int off = 32; off; off >>= 1) s += __shfl_xor(s, off);
        if (lane == 0) enorm[n] = (float)s;
        ushort4 h4, l4;
        unsigned short* hp = (unsigned short*)&h4;
        unsigned short* lp = (unsigned short*)&l4;
        #pragma unroll
        for (int j = 0; j < 4; ++j) {
            unsigned short h = f2bf(vv[j]);
            hp[j] = h;
            lp[j] = f2bf(vv[j] - bf2f(h));
        }
        *reinterpret_cast<ushort4*>(e_hi + (size_t)n * Dm + lane * 4) = h4;
        *reinterpret_cast<ushort4*>(e_lo + (size_t)n * Dm + lane * 4) = l4;
    }

    const int b  = blockIdx.x >> 5;
    const int p0 = (blockIdx.x & 31) * 32;
    const int pp = t & 31, cb = t >> 5;
    const float* zb = z + (size_t)b * (Dm * HW) + p0 + pp;
    float zs = 0.f;
    for (int ci = 0; ci < 32; ++ci) {
        int c = ci * 8 + cb;
        float x = zb[(size_t)c * HW];
        zs = fmaf(x, x, zs);
        unsigned short h = f2bf(x);
        zh[pp][c] = h;
        zl[pp][c] = f2bf(x - bf2f(h));
    }
    double d = zs;
    #pragma unroll
    for (int off = 32; off; off >>= 1) d += __shfl_xor(d, off);
    if ((t & 63) == 0) zsum[w] = d;
    __syncthreads();
    if (t == 0) zn_part[blockIdx.x] = (float)(zsum[0] + zsum[1] + zsum[2] + zsum[3]);
    const int l0 = b * 1024 + p0;
    #pragma unroll
    for (int r = 0; r < 8; ++r) {
        int id = r * 256 + t;
        int row = id >> 6, ch = id & 63;
        *reinterpret_cast<ushort4*>(z_hi + (size_t)(l0 + row) * Dm + ch * 4) =
            *reinterpret_cast<ushort4*>(&zh[row][ch * 4]);
        *reinterpret_cast<ushort4*>(z_lo + (size_t)(l0 + row) * Dm + ch * 4) =
            *reinterpret_cast<ushort4*>(&zl[row][ch * 4]);
    }
}

// ---------------- K2: bf16-split score GEMM + top-2 argmin ----------------
// r11-proven structure; single variable change: wave decomposition 8x(64x32) ->
// 4x(64x64) (acc 4x4, 256 threads). Staging bytes/order/swizzle, BK=64, block
// tile 128x128, 2-buffer LDS, carried (pnt,pkt) counters all identical to r11.
// LDS-read:MFMA ratio 0.094 -> 0.0625 B/MAC (parity with matrix pipe).
__global__ __launch_bounds__(256, 2) void k_score3(
    const unsigned short* __restrict__ z_hi, const unsigned short* __restrict__ z_lo,
    const unsigned short* __restrict__ e_hi, const unsigned short* __restrict__ e_lo,
    const float* __restrict__ enorm,
    float* __restrict__ pd1, float* __restrict__ pd2, int* __restrict__ pi1)
{
    __shared__ unsigned short lds[2][2][128 * 64];   // [buf][A=0/B=1][row*64+k]

    const int t    = threadIdx.x;
    const int lane = t & 63, w = t >> 6;             // w: 0..3
    const int wm = w >> 1, wc = w & 1;
    const int c15 = lane & 15, g4 = lane >> 4;

    const int bx = blockIdx.x;
    const int wg = (bx & 7) * 64 + (bx >> 3);
    const int mi = wg >> 1, ni = wg & 1;
    const int l0 = mi * 128;
    const int nbase = ni * 1024;

    // staging descriptors: 256 threads, 4 rounds of 32 rows; same addresses,
    // same swizzle chg, same A,B interleave per round as r11.
    const int srow = t >> 3;                  // 0..31
    const int chg  = (t & 7) ^ (srow & 7);
    const int aoff0 = (l0 + srow) * Dm + chg * 8;
    const int bbas0 = srow * Dm + chg * 8 + nbase * Dm;
    const int ld0 = t * 8;

    auto stage = [&](int buf, const unsigned short* As, const unsigned short* Bs,
                     int ntoff, int k0) {
        GLL(As + aoff0 + k0,                   &lds[buf][0][ld0]);
        GLL(Bs + bbas0 + ntoff + k0,           &lds[buf][1][ld0]);
        GLL(As + aoff0 + 32 * Dm + k0,         &lds[buf][0][ld0 + 2048]);
        GLL(Bs + bbas0 + ntoff + 32 * Dm + k0, &lds[buf][1][ld0 + 2048]);
        GLL(As + aoff0 + 64 * Dm + k0,         &lds[buf][0][ld0 + 4096]);
        GLL(Bs + bbas0 + ntoff + 64 * Dm + k0, &lds[buf][1][ld0 + 4096]);
        GLL(As + aoff0 + 96 * Dm + k0,         &lds[buf][0][ld0 + 6144]);
        GLL(Bs + bbas0 + ntoff + 96 * Dm + k0, &lds[buf][1][ld0 + 6144]);
    };

    float d1[4][4], d2[4][4]; int i1[4][4];
    #pragma unroll
    for (int m = 0; m < 4; ++m)
        #pragma unroll
        for (int r = 0; r < 4; ++r) { d1[m][r] = 3.4e38f; d2[m][r] = 3.4e38f; i1[m][r] = 0; }

    stage(0, z_hi, e_hi, 0, 0);
    __syncthreads();

    int cur = 0, it = 0;
    int pnt = 0, pkt = 1;   // (nt, kt) of the next chunk to stage
    for (int nt = 0; nt < 8; ++nt) {
        f32x4 acc[4][4];
        #pragma unroll
        for (int m = 0; m < 4; ++m)
            #pragma unroll
            for (int n = 0; n < 4; ++n) acc[m][n] = (f32x4){0.f, 0.f, 0.f, 0.f};

        for (int kt = 0; kt < 12; ++kt, ++it) {
            if (it + 1 < 96) {
                const int nterm = pkt >> 2, nkc = pkt & 3;
                const unsigned short* As = (nterm == 1) ? z_lo : z_hi;
                const unsigned short* Bs = (nterm == 2) ? e_lo : e_hi;
                stage(cur ^ 1, As, Bs, pnt << 15, nkc << 6);
                if (++pkt == 12) { pkt = 0; ++pnt; }
            }
            const unsigned short* Ab = &lds[cur][0][0];
            const unsigned short* Bb = &lds[cur][1][0];
            #pragma unroll
            for (int ks = 0; ks < 2; ++ks) {
                bf16x8 af[4], bfr[4];
                #pragma unroll
                for (int m = 0; m < 4; ++m) {
                    int row = wm * 64 + m * 16 + c15;
                    int cc  = ks * 4 + g4;
                    af[m] = *reinterpret_cast<const bf16x8*>(
                        &Ab[row * 64 + ((cc ^ (row & 7)) << 3)]);
                }
                #pragma unroll
                for (int n = 0; n < 4; ++n) {
                    int row = wc * 64 + n * 16 + c15;
                    int cc  = ks * 4 + g4;
                    bfr[n] = *reinterpret_cast<const bf16x8*>(
                        &Bb[row * 64 + ((cc ^ (row & 7)) << 3)]);
                }
                __builtin_amdgcn_s_setprio(1);
                #pragma unroll
                for (int m = 0; m < 4; ++m)
                    #pragma unroll
                    for (int n = 0; n < 4; ++n)
                        acc[m][n] = __builtin_amdgcn_mfma_f32_16x16x32_bf16(
                            af[m], bfr[n], acc[m][n], 0, 0, 0);
                __builtin_amdgcn_s_setprio(0);
            }
            __syncthreads();
            cur ^= 1;
        }
        // distances + running top-2 (codes ascend per lane -> lowest idx on tie)
        int n0 = nbase + nt * 128;
        #pragma unroll
        for (int n = 0; n < 4; ++n) {
            int ng = n0 + wc * 64 + n * 16 + c15;
            float en = enorm[ng];
            #pragma unroll
            for (int m = 0; m < 4; ++m)
                #pragma unroll
                for (int r = 0; r < 4; ++r) {
                    float s = fmaf(-2.f, acc[m][n][r], en);
                    if (s < d1[m][r]) { d2[m][r] = d1[m][r]; d1[m][r] = s; i1[m][r] = ng; }
                    else if (s < d2[m][r]) d2[m][r] = s;
                }
        }
    }

    // merge across the 16 code-lanes (c15); queries depend on g4 only
    #pragma unroll
    for (int off = 1; off <= 8; off <<= 1) {
        #pragma unroll
        for (int m = 0; m < 4; ++m)
            #pragma unroll
            for (int r = 0; r < 4; ++r) {
                float od1 = __shfl_xor(d1[m][r], off);
                int   oi1 = __shfl_xor(i1[m][r], off);
                float od2 = __shfl_xor(d2[m][r], off);
                float nd2 = fminf(fminf(d2[m][r], od2), fmaxf(d1[m][r], od1));
                if (od1 < d1[m][r] || (od1 == d1[m][r] && oi1 < i1[m][r])) {
                    d1[m][r] = od1; i1[m][r] = oi1;
                }
                d2[m][r] = nd2;
            }
    }

    // cross-wave merge over wc (2 waves share queries); write per-ni partials
    float* rs1 = (float*)&lds[0][0][0];
    float* rs2 = rs1 + 128;
    int*   ri  = (int*)(rs2 + 128);
    if (wc == 1 && c15 == 0) {
        #pragma unroll
        for (int m = 0; m < 4; ++m)
            #pragma unroll
            for (int r = 0; r < 4; ++r) {
                int q = wm * 64 + m * 16 + g4 * 4 + r;
                rs1[q] = d1[m][r];
                rs2[q] = d2[m][r];
                ri [q] = i1[m][r];
            }
    }
    __syncthreads();
    if (wc == 0 && c15 == 0) {
        #pragma unroll
        for (int m = 0; m < 4; ++m)
            #pragma unroll
            for (int r = 0; r < 4; ++r) {
                int q = wm * 64 + m * 16 + g4 * 4 + r;
                float bd1 = d1[m][r], bd2 = d2[m][r]; int bi1 = i1[m][r];
                float od1 = rs1[q], od2 = rs2[q];
                int   oi1 = ri [q];
                float nd2 = fminf(fminf(bd2, od2), fmaxf(bd1, od1));
                if (od1 < bd1 || (od1 == bd1 && oi1 < bi1)) { bd1 = od1; bi1 = oi1; }
                bd2 = nd2;
                int gq = l0 + q;
                pd1[ni * L_TOT + gq] = bd1;
                pd2[ni * L_TOT + gq] = bd2;
                pi1[ni * L_TOT + gq] = bi1;
            }
    }
}

// ---------------- fused merge + gather (tier 1) ----------------
__global__ __launch_bounds__(256) void k_mg(
    const float* __restrict__ pd1, const float* __restrict__ pd2,
    const int* __restrict__ pi1, const float* __restrict__ emb,
    int* __restrict__ ws_idx, float* __restrict__ out_idxf,
    float* __restrict__ used, int* __restrict__ flag_cnt,
    int* __restrict__ flag_list, float* __restrict__ d1_part,
    float* __restrict__ outq)
{
    __shared__ int sidx[64];
    __shared__ float eldT[Dm][65];
    const int t = threadIdx.x;
    const int l0 = blockIdx.x * 64;
    const int b = l0 >> 10, p0 = l0 & 1023;

    if (t < 64) {
        int gq = l0 + t;
        float d1 = pd1[gq], d2 = pd2[gq]; int i1 = pi1[gq];
        float od1 = pd1[L_TOT + gq], od2 = pd2[L_TOT + gq];
        int   oi1 = pi1[L_TOT + gq];
        float nd2 = fminf(fminf(d2, od2), fmaxf(d1, od1));
        if (od1 < d1 || (od1 == d1 && oi1 < i1)) { d1 = od1; i1 = oi1; }
        d2 = nd2;
        ws_idx[gq] = i1;
        out_idxf[gq] = (float)i1;
        if (d2 - d1 < TAU) {
            int pos = atomicAdd(flag_cnt, 1);
            flag_list[pos] = gq;
        } else {
            used[i1] = 1.0f;
        }
        sidx[t] = i1;
        float s = d1;
        #pragma unroll
        for (int off = 32; off; off >>= 1) s += __shfl_xor(s, off);
        if (t == 0) d1_part[blockIdx.x] = s;
    }
    __syncthreads();

    int w = t >> 6, lane = t & 63;
    for (int r = 0; r < 16; ++r) {
        int q = r * 4 + w;
        const float4 v = *reinterpret_cast<const float4*>(emb + (size_t)sidx[q] * Dm + lane * 4);
        eldT[lane * 4 + 0][q] = v.x; eldT[lane * 4 + 1][q] = v.y;
        eldT[lane * 4 + 2][q] = v.z; eldT[lane * 4 + 3][q] = v.w;
    }
    __syncthreads();
    const size_t obase = (size_t)b * (Dm * HW) + p0 + lane;
    #pragma unroll 4
    for (int it = 0; it < 64; ++it) {
        int c = w * 64 + it;
        outq[obase + (size_t)c * HW] = eldT[c][lane];
    }
}

// ---------------- merge only (tier 2, r7-proven) ----------------
__global__ __launch_bounds__(256) void k_merge(
    const float* __restrict__ pd1, const float* __restrict__ pd2,
    const int* __restrict__ pi1, int* __restrict__ ws_idx,
    float* __restrict__ out_idxf, float* __restrict__ used,
    int* __restrict__ flag_cnt, int* __restrict__ flag_list,
    float* __restrict__ d1_part)
{
    __shared__ float sdl[256];
    int tt = threadIdx.x;
    int gq = blockIdx.x * 256 + tt;
    float d1 = pd1[gq], d2 = pd2[gq]; int i1 = pi1[gq];
    {
        float od1 = pd1[L_TOT + gq], od2 = pd2[L_TOT + gq];
        int   oi1 = pi1[L_TOT + gq];
        float nd2 = fminf(fminf(d2, od2), fmaxf(d1, od1));
        if (od1 < d1 || (od1 == d1 && oi1 < i1)) { d1 = od1; i1 = oi1; }
        d2 = nd2;
    }
    ws_idx[gq] = i1;
    out_idxf[gq] = (float)i1;
    if (d2 - d1 < TAU) {
        int pos = atomicAdd(flag_cnt, 1);
        flag_list[pos] = gq;
    } else {
        used[i1] = 1.0f;
    }
    sdl[tt] = d1;
    __syncthreads();
    for (int st = 128; st; st >>= 1) {
        if (tt < st) sdl[tt] += sdl[tt + st];
        __syncthreads();
    }
    if (tt == 0) d1_part[blockIdx.x] = sdl[0];
}

// ---------------- fallback fp32 argmin (round-1 proven) ----------------
#define BM 64
#define BN 128
#define BK 64
__global__ __launch_bounds__(256, 2) void k_argmin_f32(
    const float* __restrict__ z, const float* __restrict__ emb,
    const float* __restrict__ enorm, int* __restrict__ ws_idx,
    float* __restrict__ out_idxf, float* __restrict__ used,
    int* __restrict__ flag_cnt, int* __restrict__ flag_list)
{
    __shared__ float zl[BK][BM];
    __shared__ float el[BK][BN + 4];
    __shared__ float rd1[4][64];
    __shared__ int   ri1[4][64];
    __shared__ float rd2[4][64];

    const int t  = threadIdx.x;
    const int tq = t & 15;
    const int tn = t >> 4;
    const int l0 = blockIdx.x * BM;
    const int b  = l0 >> 10, p0 = l0 & 1023;
    const float* zb = z + (size_t)b * (Dm * HW) + p0;

    float d1[4], d2[4]; int i1[4];
    #pragma unroll
    for (int i = 0; i < 4; ++i) { d1[i] = FLT_MAX; d2[i] = FLT_MAX; i1[i] = 0; }

    for (int nt = 0; nt < NE / BN; ++nt) {
        const int n0 = nt * BN;
        float acc[4][8];
        #pragma unroll
        for (int i = 0; i < 4; ++i)
            #pragma unroll
            for (int j = 0; j < 8; ++j) acc[i][j] = 0.f;

        for (int kc = 0; kc < Dm / BK; ++kc) {
            __syncthreads();
            #pragma unroll
            for (int r = 0; r < 4; ++r) {
                int f = r * 256 + t;
                int kk = f >> 4, q4 = (f & 15) << 2;
                float4 v = *reinterpret_cast<const float4*>(zb + (size_t)(kc * BK + kk) * HW + q4);
                *reinterpret_cast<float4*>(&zl[kk][q4]) = v;
            }
            #pragma unroll
            for (int r = 0; r < 8; ++r) {
                int f = r * 256 + t;
                int n = f >> 4, k4 = (f & 15) << 2;
                float4 v = *reinterpret_cast<const float4*>(emb + (size_t)(n0 + n) * Dm + kc * BK + k4);
                el[k4 + 0][n] = v.x; el[k4 + 1][n] = v.y;
                el[k4 + 2][n] = v.z; el[k4 + 3][n] = v.w;
            }
            __syncthreads();
            #pragma unroll 4
            for (int kk = 0; kk < BK; ++kk) {
                float4 zf = *reinterpret_cast<const float4*>(&zl[kk][tq << 2]);
                float4 e0 = *reinterpret_cast<const float4*>(&el[kk][tn << 3]);
                float4 e1 = *reinterpret_cast<const float4*>(&el[kk][(tn << 3) + 4]);
                float zr[4] = { zf.x, zf.y, zf.z, zf.w };
                float er[8] = { e0.x, e0.y, e0.z, e0.w, e1.x, e1.y, e1.z, e1.w };
                #pragma unroll
                for (int i = 0; i < 4; ++i)
                    #pragma unroll
                    for (int j = 0; j < 8; ++j)
                        acc[i][j] = fmaf(zr[i], er[j], acc[i][j]);
            }
        }
        #pragma unroll
        for (int j = 0; j < 8; ++j) {
            int ng = n0 + (tn << 3) + j;
            float en = enorm[ng];
            #pragma unroll
            for (int i = 0; i < 4; ++i) {
                float s = fmaf(-2.f, acc[i][j], en);
                if (s < d1[i]) { d2[i] = d1[i]; d1[i] = s; i1[i] = ng; }
                else if (s < d2[i]) d2[i] = s;
            }
        }
    }
    #pragma unroll
    for (int off = 16; off <= 32; off <<= 1) {
        #pragma unroll
        for (int i = 0; i < 4; ++i) {
            float od1 = __shfl_xor(d1[i], off);
            int   oi1 = __shfl_xor(i1[i], off);
            float od2 = __shfl_xor(d2[i], off);
            float nd2 = fminf(fminf(d2[i], od2), fmaxf(d1[i], od1));
            bool take = (od1 < d1[i]) || (od1 == d1[i] && oi1 < i1[i]);
            if (take) { d1[i] = od1; i1[i] = oi1; }
            d2[i] = nd2;
        }
    }
    int w = t >> 6;
    if ((t & 63) < 16) {
        #pragma unroll
        for (int i = 0; i < 4; ++i) {
            rd1[w][(tq << 2) + i] = d1[i];
            ri1[w][(tq << 2) + i] = i1[i];
            rd2[w][(tq << 2) + i] = d2[i];
        }
    }
    __syncthreads();
    if (t < 64) {
        float bd1 = rd1[0][t]; int bi1 = ri1[0][t]; float bd2 = rd2[0][t];
        #pragma unroll
        for (int ww = 1; ww < 4; ++ww) {
            float od1 = rd1[ww][t]; int oi1 = ri1[ww][t]; float od2 = rd2[ww][t];
            float nd2 = fminf(fminf(bd2, od2), fmaxf(bd1, od1));
            if (od1 < bd1 || (od1 == bd1 && oi1 < bi1)) { bd1 = od1; bi1 = oi1; }
            bd2 = nd2;
        }
        int l = l0 + t;
        ws_idx[l] = bi1;
        out_idxf[l] = (float)bi1;
        if (bd2 - bd1 < TAU) {
            int pos = atomicAdd(flag_cnt, 1);
            flag_list[pos] = l;
        } else {
            used[bi1] = 1.0f;
        }
    }
}

// ---------------- K_refine: fp64-exact argmin (r8-proven) + outq row patch ----------------
__global__ void k_refine(const float* __restrict__ z, const float* __restrict__ emb,
                         const int* __restrict__ flag_cnt, const int* __restrict__ flag_list,
                         int* __restrict__ ws_idx, float* __restrict__ out_idxf,
                         float* __restrict__ used, float* __restrict__ outq)
{
    __shared__ float zrow[Dm];
    __shared__ double sd[256];
    __shared__ int    si[256];
    int nf = *flag_cnt;
    for (int fi = blockIdx.x; fi < nf; fi += gridDim.x) {
        int l = flag_list[fi];
        int b = l >> 10, p = l & 1023;
        const float* zq = z + (size_t)b * (Dm * HW) + p;
        __syncthreads();
        for (int c = threadIdx.x; c < Dm; c += blockDim.x) zrow[c] = zq[(size_t)c * HW];
        __syncthreads();
        double bd = DBL_MAX; int bi = 0;
        for (int nb = 0; nb < NE / 256; ++nb) {
            int n = nb * 256 + threadIdx.x;
            const float* er = emb + (size_t)n * Dm;
            double dt0 = 0.0, dt1 = 0.0, dt2 = 0.0, dt3 = 0.0;
            double nm0 = 0.0, nm1 = 0.0, nm2 = 0.0, nm3 = 0.0;
            for (int c = 0; c < Dm; c += 4) {
                double e0 = er[c], e1 = er[c + 1], e2 = er[c + 2], e3 = er[c + 3];
                dt0 += e0 * (double)zrow[c];     nm0 += e0 * e0;
                dt1 += e1 * (double)zrow[c + 1]; nm1 += e1 * e1;
                dt2 += e2 * (double)zrow[c + 2]; nm2 += e2 * e2;
                dt3 += e3 * (double)zrow[c + 3]; nm3 += e3 * e3;
            }
            double s = (nm0 + nm1) + (nm2 + nm3) - 2.0 * ((dt0 + dt1) + (dt2 + dt3));
            if (s < bd) { bd = s; bi = n; }
        }
        sd[threadIdx.x] = bd; si[threadIdx.x] = bi;
        __syncthreads();
        for (int st = 128; st; st >>= 1) {
            if (threadIdx.x < (unsigned)st) {
                double od = sd[threadIdx.x + st]; int oi = si[threadIdx.x + st];
                if (od < sd[threadIdx.x] || (od == sd[threadIdx.x] && oi < si[threadIdx.x])) {
                    sd[threadIdx.x] = od; si[threadIdx.x] = oi;
                }
            }
            __syncthreads();
        }
        if (threadIdx.x == 0) {
            ws_idx[l] = si[0];
            out_idxf[l] = (float)si[0];
            used[si[0]] = 1.0f;
        }
        __syncthreads();
        int bi0 = si[0];
        int c = threadIdx.x;
        outq[(size_t)b * (Dm * HW) + (size_t)c * HW + p] = emb[(size_t)bi0 * Dm + c];
        __syncthreads();
    }
}

// ---------------- gather (tier 2, post-refine) ----------------
__global__ __launch_bounds__(256) void k_gather(
    const float* __restrict__ emb, const int* __restrict__ ws_idx,
    float* __restrict__ outq)
{
    __shared__ int sidx[64];
    __shared__ float eldT[Dm][65];
    const int t = threadIdx.x;
    const int l0 = blockIdx.x * 64;
    const int b = l0 >> 10, p0 = l0 & 1023;
    if (t < 64) sidx[t] = ws_idx[l0 + t];
    __syncthreads();
    int w = t >> 6, lane = t & 63;
    for (int r = 0; r < 16; ++r) {
        int q = r * 4 + w;
        const float4 v = *reinterpret_cast<const float4*>(emb + (size_t)sidx[q] * Dm + lane * 4);
        eldT[lane * 4 + 0][q] = v.x; eldT[lane * 4 + 1][q] = v.y;
        eldT[lane * 4 + 2][q] = v.z; eldT[lane * 4 + 3][q] = v.w;
    }
    __syncthreads();
    const size_t obase = (size_t)b * (Dm * HW) + p0 + lane;
    #pragma unroll 4
    for (int it = 0; it < 64; ++it) {
        int c = w * 64 + it;
        outq[obase + (size_t)c * HW] = eldT[c][lane];
    }
}

// ---------------- fallback gather+loss (tier 3) ----------------
__global__ __launch_bounds__(256) void k_gather_loss(
    const float* __restrict__ z, const float* __restrict__ emb,
    const int* __restrict__ ws_idx, float* __restrict__ outq,
    float* __restrict__ partials)
{
    __shared__ int sidx[64];
    __shared__ float eldT[Dm][65];
    __shared__ float wsum[4];
    const int t = threadIdx.x;
    const int l0 = blockIdx.x * 64;
    const int b = l0 >> 10, p0 = l0 & 1023;
    if (t < 64) sidx[t] = ws_idx[l0 + t];
    __syncthreads();
    int w = t >> 6, lane = t & 63;
    for (int r = 0; r < 16; ++r) {
        int q = r * 4 + w;
        const float4 v = *reinterpret_cast<const float4*>(emb + (size_t)sidx[q] * Dm + lane * 4);
        eldT[lane * 4 + 0][q] = v.x; eldT[lane * 4 + 1][q] = v.y;
        eldT[lane * 4 + 2][q] = v.z; eldT[lane * 4 + 3][q] = v.w;
    }
    __syncthreads();
    float ls = 0.f;
    const size_t obase = (size_t)b * (Dm * HW) + p0 + lane;
    for (int it = 0; it < 64; ++it) {
        int c = w * 64 + it;
        size_t o = obase + (size_t)c * HW;
        float qv = eldT[c][lane];
        float zv = z[o];
        outq[o] = qv;
        float df = qv - zv;
        ls = fmaf(df, df, ls);
    }
    #pragma unroll
    for (int off = 32; off; off >>= 1) ls += __shfl_xor(ls, off);
    if (lane == 0) wsum[w] = ls;
    __syncthreads();
    if (t == 0) partials[blockIdx.x] = wsum[0] + wsum[1] + wsum[2] + wsum[3];
}

// ---------------- final: loss = (Sum||z||^2 + Sum d1)/count, used count ----------------
__global__ void k_final(const float* __restrict__ zn_part, const float* __restrict__ d1_part,
                        int nd1, const float* __restrict__ used,
                        float* __restrict__ out_loss, float* __restrict__ out_used)
{
    __shared__ double s1[256];
    __shared__ float  s2[256];
    int t = threadIdx.x;
    double a = 0.0;
    for (int i = t; i < 1024; i += 256) a += (double)zn_part[i];
    for (int i = t; i < nd1; i += 256) a += (double)d1_part[i];
    float u = 0.f;
    for (int i = t; i < NE; i += 256) u += used[i];
    s1[t] = a; s2[t] = u;
    __syncthreads();
    for (int st = 128; st; st >>= 1) {
        if (t < st) { s1[t] += s1[t + st]; s2[t] += s2[t + st]; }
        __syncthreads();
    }
    if (t == 0) { *out_loss = (float)(s1[0] / 8388608.0); *out_used = s2[0]; }
}

// ---------------- fallback final ----------------
__global__ void k_final_fb(const float* __restrict__ partials, const float* __restrict__ used,
                           float* __restrict__ out_loss, float* __restrict__ out_used)
{
    __shared__ float s1[256], s2[256];
    int t = threadIdx.x;
    float a = partials[t] + partials[t + 256];
    float u = 0.f;
    for (int i = t; i < NE; i += 256) u += used[i];
    s1[t] = a; s2[t] = u;
    __syncthreads();
    for (int st = 128; st; st >>= 1) {
        if (t < st) { s1[t] += s1[t + st]; s2[t] += s2[t + st]; }
        __syncthreads();
    }
    if (t == 0) { *out_loss = s1[0] / 8388608.f; *out_used = s2[0]; }
}

extern "C" void kernel_launch(void* const* d_in, const int* in_sizes, int n_in,
                              void* d_out, int out_size, void* d_ws, size_t ws_size,
                              hipStream_t stream) {
    const float* z   = (const float*)d_in[0];
    const float* emb = (const float*)d_in[1];
    float* out      = (float*)d_out;
    float* outq     = out;
    float* out_loss = out + QOFF;
    float* out_idxf = out + QOFF + 1;
    float* out_used = out + QOFF + 1 + L_TOT;

    float* ws       = (float*)d_ws;
    float* enorm    = ws;                         // [0, 2048)
    float* used     = ws + 2048;                  // [2048, 4096)
    float* zn_part  = ws + 4096;                  // [4096, 5120)
    float* d1_part  = ws + 5120;                  // [5120, 5632)  512
    int*   flag_cnt = (int*)(ws + 5632);          // 1 (+pad)
    int*   ws_idx   = (int*)(ws + 5888);          // 32768
    int*   flag_list= (int*)(ws + 5888 + L_TOT);  // 32768 -> ends 71424

    // tier-1 partials in ws (avoids outq read/write race in fused k_mg)
    float* pd1w = ws + 71680;                     // 65536
    float* pd2w = ws + 137216;                    // 65536
    int*   pi1w = (int*)(ws + 202752);            // 65536 -> ends 268288 floats

    size_t bf_bytes = 2ull * (NE + L_TOT) * Dm * sizeof(unsigned short);  // 35651584
    size_t need_t1 = 268288ull * 4 + bf_bytes;    // ~36.7 MB
    size_t need_t2 = 71680ull * 4 + bf_bytes;     // ~35.9 MB

    if (ws_size >= need_t1) {
        unsigned short* e_hi = (unsigned short*)(ws + 268288);
        unsigned short* e_lo = e_hi + (size_t)NE * Dm;
        unsigned short* z_hi = e_lo + (size_t)NE * Dm;
        unsigned short* z_lo = z_hi + (size_t)L_TOT * Dm;
        k_split<<<1024, 256, 0, stream>>>(z, emb, z_hi, z_lo, e_hi, e_lo,
                                          enorm, zn_part, used, flag_cnt);
        k_score3<<<512, 256, 0, stream>>>(z_hi, z_lo, e_hi, e_lo, enorm, pd1w, pd2w, pi1w);
        k_mg<<<L_TOT / 64, 256, 0, stream>>>(pd1w, pd2w, pi1w, emb, ws_idx, out_idxf,
                                             used, flag_cnt, flag_list, d1_part, outq);
        k_refine<<<256, 256, 0, stream>>>(z, emb, flag_cnt, flag_list, ws_idx, out_idxf,
                                          used, outq);
        k_final<<<1, 256, 0, stream>>>(zn_part, d1_part, 512, used, out_loss, out_used);
    } else if (ws_size >= need_t2) {
        unsigned short* e_hi = (unsigned short*)(ws + 71680);
        unsigned short* e_lo = e_hi + (size_t)NE * Dm;
        unsigned short* z_hi = e_lo + (size_t)NE * Dm;
        unsigned short* z_lo = z_hi + (size_t)L_TOT * Dm;
        float* pd1 = outq;
        float* pd2 = outq + 2 * L_TOT;
        int*   pi1 = (int*)(outq + 4 * L_TOT);
        k_split<<<1024, 256, 0, stream>>>(z, emb, z_hi, z_lo, e_hi, e_lo,
                                          enorm, zn_part, used, flag_cnt);
        k_score3<<<512, 256, 0, stream>>>(z_hi, z_lo, e_hi, e_lo, enorm, pd1, pd2, pi1);
        k_merge<<<L_TOT / 256, 256, 0, stream>>>(pd1, pd2, pi1, ws_idx, out_idxf, used,
                                                 flag_cnt, flag_list, d1_part);
        k_refine<<<256, 256, 0, stream>>>(z, emb, flag_cnt, flag_list, ws_idx, out_idxf,
                                          used, outq);
        k_gather<<<L_TOT / 64, 256, 0, stream>>>(emb, ws_idx, outq);
        k_final<<<1, 256, 0, stream>>>(zn_part, d1_part, 128, used, out_loss, out_used);
    } else {
        hipMemsetAsync(used, 0, (size_t)3584 * 4, stream);
        k_enorm<<<NE / 4, 256, 0, stream>>>(emb, enorm);
        k_argmin_f32<<<L_TOT / BM, 256, 0, stream>>>(z, emb, enorm, ws_idx, out_idxf, used,
                                                     flag_cnt, flag_list);
        k_refine<<<256, 256, 0, stream>>>(z, emb, flag_cnt, flag_list, ws_idx, out_idxf,
                                          used, outq);
        k_gather_loss<<<L_TOT / 64, 256, 0, stream>>>(z, emb, ws_idx, outq, zn_part);
        k_final_fb<<<1, 256, 0, stream>>>(zn_part, used, out_loss, out_used);
    }
}